// Round 1
// baseline (882.664 us; speedup 1.0000x reference)
//
#include <hip/hip_runtime.h>
#include <hip/hip_bf16.h>

// ---------------------------------------------------------------------------
// InductiveBundleMapLearner: 2x SAGEConv (mean) -> linear -> Cayley map
// N=50000, E=800000, 512 -> 256 -> 128 -> 28 params -> [N,8,8] orthogonal
//
// Structure:
//   1. CSR build by dst (histogram -> scan -> scatter)
//   2. GEMM1: y = x @ [W1l;W1r]^T            [N,512]
//   3. agg1:  h1 = relu(mean(y_l) + y_r + b1) [N,256]
//   4. GEMM2: z = h1 @ [W2l;W2r]^T           [N,256]
//   5. agg2:  h2 = relu(mean(z_l) + z_r + b2) [N,128]
//   6. final: p = h2 @ Wp^T + bp; O = (I-A)^{-1}(I+A)  [N,8,8]
// ---------------------------------------------------------------------------

#define WS_ALIGN(x) (((x) + 255) & ~size_t(255))

// ---------------- CSR build ----------------

__global__ void hist_kernel(const int* __restrict__ dst, int* __restrict__ deg, int E) {
    int e = blockIdx.x * blockDim.x + threadIdx.x;
    if (e < E) atomicAdd(&deg[dst[e]], 1);
}

__global__ void scan_kernel(const int* __restrict__ deg, int* __restrict__ rowptr, int n) {
    __shared__ int sh[1024];
    __shared__ int carry_s;
    int tid = threadIdx.x;
    if (tid == 0) carry_s = 0;
    __syncthreads();
    for (int base = 0; base < n; base += 1024) {
        int i = base + tid;
        int v = (i < n) ? deg[i] : 0;
        sh[tid] = v;
        __syncthreads();
        for (int off = 1; off < 1024; off <<= 1) {
            int t = (tid >= off) ? sh[tid - off] : 0;
            __syncthreads();
            sh[tid] += t;
            __syncthreads();
        }
        int incl = sh[tid];
        int carry = carry_s;
        if (i < n) rowptr[i] = carry + incl - v;   // exclusive
        __syncthreads();
        if (tid == 1023) carry_s = carry + incl;
        __syncthreads();
    }
    if (tid == 0) rowptr[n] = carry_s;
}

__global__ void scatter_kernel(const int* __restrict__ src, const int* __restrict__ dst,
                               const int* __restrict__ rowptr, int* __restrict__ cursor,
                               int* __restrict__ adj, int E) {
    int e = blockIdx.x * blockDim.x + threadIdx.x;
    if (e < E) {
        int d = dst[e];
        int p = atomicAdd(&cursor[d], 1);
        adj[rowptr[d] + p] = src[e];
    }
}

// ---------------- fp32 tiled GEMM: C = X @ W^T ----------------
// W rows come from Wa (rows [0,splitN)) and Wb (rows [splitN,Ncols)).
// BM=BN=64, BK=32, 256 threads, 4x4 micro-tile.

__global__ __launch_bounds__(256)
void gemm_xwT(const float* __restrict__ X,   // [M,K]
              const float* __restrict__ Wa,  // [splitN, K]
              const float* __restrict__ Wb,  // [Ncols-splitN, K]
              float* __restrict__ C,         // [M, Ncols]
              int M, int K, int Ncols, int splitN) {
    __shared__ float As[32][68];   // [k][row], +4 pad: 4-way max conflict on writes
    __shared__ float Bs[32][68];   // [k][col]
    const int row0 = blockIdx.x * 64;
    const int col0 = blockIdx.y * 64;
    const int tid = threadIdx.x;
    const int tx = tid & 15, ty = tid >> 4;

    const int a_r = tid >> 3;          // 0..31
    const int a_k = (tid & 7) * 4;     // 0..28

    float acc[4][4] = {};

    for (int k0 = 0; k0 < K; k0 += 32) {
#pragma unroll
        for (int h = 0; h < 2; ++h) {
            int r = a_r + 32 * h;
            int grow = row0 + r;
            float4 v = make_float4(0.f, 0.f, 0.f, 0.f);
            if (grow < M) v = *reinterpret_cast<const float4*>(&X[(size_t)grow * K + k0 + a_k]);
            As[a_k + 0][r] = v.x; As[a_k + 1][r] = v.y;
            As[a_k + 2][r] = v.z; As[a_k + 3][r] = v.w;
        }
#pragma unroll
        for (int h = 0; h < 2; ++h) {
            int j = a_r + 32 * h;
            int gcol = col0 + j;
            const float* wrow = (gcol < splitN) ? &Wa[(size_t)gcol * K]
                                                : &Wb[(size_t)(gcol - splitN) * K];
            float4 v = *reinterpret_cast<const float4*>(&wrow[k0 + a_k]);
            Bs[a_k + 0][j] = v.x; Bs[a_k + 1][j] = v.y;
            Bs[a_k + 2][j] = v.z; Bs[a_k + 3][j] = v.w;
        }
        __syncthreads();
#pragma unroll
        for (int k = 0; k < 32; ++k) {
            float4 a = *reinterpret_cast<const float4*>(&As[k][ty * 4]);
            float4 b = *reinterpret_cast<const float4*>(&Bs[k][tx * 4]);
            float av[4] = {a.x, a.y, a.z, a.w};
            float bv[4] = {b.x, b.y, b.z, b.w};
#pragma unroll
            for (int i = 0; i < 4; ++i)
#pragma unroll
                for (int j = 0; j < 4; ++j)
                    acc[i][j] += av[i] * bv[j];
        }
        __syncthreads();
    }
#pragma unroll
    for (int i = 0; i < 4; ++i) {
        int r = row0 + ty * 4 + i;
        if (r < M) {
            float4 o = make_float4(acc[i][0], acc[i][1], acc[i][2], acc[i][3]);
            *reinterpret_cast<float4*>(&C[(size_t)r * Ncols + col0 + tx * 4]) = o;
        }
    }
}

// ---------------- aggregation: h = relu(mean_l + self_r + b) ----------------
// Y = [N, 2F]: cols [0,F) = lin_l transform, [F,2F) = lin_r transform.
// One wave per node; lane handles VEC consecutive channels (64*VEC == F).

template <int VEC>
__global__ __launch_bounds__(256)
void aggregate_kernel(const float* __restrict__ Y, const float* __restrict__ bias,
                      const int* __restrict__ rowptr, const int* __restrict__ adj,
                      float* __restrict__ H, int n, int F) {
    int wave = threadIdx.x >> 6;
    int lane = threadIdx.x & 63;
    int node = blockIdx.x * 4 + wave;
    if (node >= n) return;
    int c = lane * VEC;
    int start = rowptr[node], end = rowptr[node + 1];
    const int twoF = 2 * F;
    float acc[VEC];
#pragma unroll
    for (int v = 0; v < VEC; ++v) acc[v] = 0.f;
    for (int e = start; e < end; ++e) {
        int s = adj[e];
        const float* row = &Y[(size_t)s * twoF + c];
        if constexpr (VEC == 4) {
            float4 r = *reinterpret_cast<const float4*>(row);
            acc[0] += r.x; acc[1] += r.y; acc[2] += r.z; acc[3] += r.w;
        } else {
            float2 r = *reinterpret_cast<const float2*>(row);
            acc[0] += r.x; acc[1] += r.y;
        }
    }
    int d = end - start;
    float inv = 1.0f / (float)(d > 0 ? d : 1);
    const float* self = &Y[(size_t)node * twoF + F + c];
#pragma unroll
    for (int v = 0; v < VEC; ++v) {
        float hv = acc[v] * inv + self[v] + bias[c + v];
        H[(size_t)node * F + c + v] = fmaxf(hv, 0.f);
    }
}

// ---------------- final: params + Cayley ----------------
// p = h2 @ Wp^T + bp (28 params), A skew from triu order, O = (I-A)^{-1}(I+A).
// Unpivoted Gauss-Jordan is safe: sym(I-A) = I is SPD -> pivots >= 1.

__global__ __launch_bounds__(256)
void final_kernel(const float* __restrict__ H2, const float* __restrict__ Wp,
                  const float* __restrict__ bp, float* __restrict__ Out, int n) {
    __shared__ float WpS[28 * 128];
    __shared__ float bpS[28];
    for (int t = threadIdx.x; t < 28 * 128; t += 256) WpS[t] = Wp[t];
    if (threadIdx.x < 28) bpS[threadIdx.x] = bp[threadIdx.x];
    __syncthreads();

    int i = blockIdx.x * blockDim.x + threadIdx.x;
    if (i >= n) return;

    float p[28];
#pragma unroll
    for (int j = 0; j < 28; ++j) p[j] = bpS[j];
    const float4* hp = reinterpret_cast<const float4*>(&H2[(size_t)i * 128]);
#pragma unroll
    for (int q = 0; q < 32; ++q) {
        float4 hv = hp[q];
#pragma unroll
        for (int j = 0; j < 28; ++j) {
            const float* w = &WpS[j * 128 + 4 * q];
            p[j] += hv.x * w[0] + hv.y * w[1] + hv.z * w[2] + hv.w * w[3];
        }
    }

    // M = I - A, B = I + A
    float M_[8][8], B_[8][8];
#pragma unroll
    for (int r = 0; r < 8; ++r)
#pragma unroll
        for (int c = 0; c < 8; ++c) {
            M_[r][c] = (r == c) ? 1.f : 0.f;
            B_[r][c] = (r == c) ? 1.f : 0.f;
        }
    {
        int idx = 0;
#pragma unroll
        for (int r = 0; r < 8; ++r)
#pragma unroll
            for (int c = r + 1; c < 8; ++c) {
                float a = p[idx++];
                M_[r][c] -= a;  M_[c][r] += a;
                B_[r][c] += a;  B_[c][r] -= a;
            }
    }
    // Gauss-Jordan, no pivoting, fully unrolled (all compile-time indices)
#pragma unroll
    for (int col = 0; col < 8; ++col) {
        float inv = 1.0f / M_[col][col];
#pragma unroll
        for (int c = 0; c < 8; ++c) { M_[col][c] *= inv; B_[col][c] *= inv; }
#pragma unroll
        for (int r = 0; r < 8; ++r) {
            if (r == col) continue;
            float f = M_[r][col];
#pragma unroll
            for (int c = 0; c < 8; ++c) {
                M_[r][c] -= f * M_[col][c];
                B_[r][c] -= f * B_[col][c];
            }
        }
    }
    float* out = &Out[(size_t)i * 64];
#pragma unroll
    for (int r = 0; r < 8; ++r) {
        float4 o0 = make_float4(B_[r][0], B_[r][1], B_[r][2], B_[r][3]);
        float4 o1 = make_float4(B_[r][4], B_[r][5], B_[r][6], B_[r][7]);
        *reinterpret_cast<float4*>(&out[r * 8 + 0]) = o0;
        *reinterpret_cast<float4*>(&out[r * 8 + 4]) = o1;
    }
}

// ---------------------------------------------------------------------------

extern "C" void kernel_launch(void* const* d_in, const int* in_sizes, int n_in,
                              void* d_out, int out_size, void* d_ws, size_t ws_size,
                              hipStream_t stream) {
    const float* x   = (const float*)d_in[0];
    const int*   ei  = (const int*)d_in[1];
    const float* W1l = (const float*)d_in[2];
    const float* b1  = (const float*)d_in[3];
    const float* W1r = (const float*)d_in[4];
    const float* W2l = (const float*)d_in[5];
    const float* b2  = (const float*)d_in[6];
    const float* W2r = (const float*)d_in[7];
    const float* Wp  = (const float*)d_in[8];
    const float* bp  = (const float*)d_in[9];
    float* out = (float*)d_out;

    const int IN_DIM = 512;
    const int N = in_sizes[0] / IN_DIM;   // 50000
    const int E = in_sizes[1] / 2;        // 800000

    // workspace layout
    char* ws = (char*)d_ws;
    size_t off = 0;
    int* deg    = (int*)(ws + off); off = WS_ALIGN(off + (size_t)N * 4);
    int* rowptr = (int*)(ws + off); off = WS_ALIGN(off + (size_t)(N + 1) * 4);
    int* cursor = (int*)(ws + off); off = WS_ALIGN(off + (size_t)N * 4);
    int* adj    = (int*)(ws + off); off = WS_ALIGN(off + (size_t)E * 4);
    float* bufA = (float*)(ws + off); off = WS_ALIGN(off + (size_t)N * 512 * 4);
    float* bufB = (float*)(ws + off); off = WS_ALIGN(off + (size_t)N * 256 * 4);

    const int* src = ei;
    const int* dst = ei + E;

    hipMemsetAsync(deg, 0, (size_t)N * 4, stream);
    hipMemsetAsync(cursor, 0, (size_t)N * 4, stream);

    int eb = (E + 255) / 256;
    hist_kernel<<<eb, 256, 0, stream>>>(dst, deg, E);
    scan_kernel<<<1, 1024, 0, stream>>>(deg, rowptr, N);
    scatter_kernel<<<eb, 256, 0, stream>>>(src, dst, rowptr, cursor, adj, E);

    int gm = (N + 63) / 64;   // 782

    // layer 1: y = x @ [W1l;W1r]^T  -> bufA [N,512]
    gemm_xwT<<<dim3(gm, 8), 256, 0, stream>>>(x, W1l, W1r, bufA, N, 512, 512, 256);
    // h1 = relu(mean + self + b1) -> bufB [N,256]
    aggregate_kernel<4><<<(N + 3) / 4, 256, 0, stream>>>(bufA, b1, rowptr, adj, bufB, N, 256);

    // layer 2: z = h1 @ [W2l;W2r]^T -> bufA [N,256]
    gemm_xwT<<<dim3(gm, 4), 256, 0, stream>>>(bufB, W2l, W2r, bufA, N, 256, 256, 128);
    // h2 -> bufB [N,128]
    aggregate_kernel<2><<<(N + 3) / 4, 256, 0, stream>>>(bufA, b2, rowptr, adj, bufB, N, 128);

    // params + Cayley -> out [N,8,8]
    final_kernel<<<(N + 255) / 256, 256, 0, stream>>>(bufB, Wp, bp, out, N);
}

// Round 2
// 479.964 us; speedup vs baseline: 1.8390x; 1.8390x over previous
//
#include <hip/hip_runtime.h>
#include <hip/hip_bf16.h>

// ---------------------------------------------------------------------------
// InductiveBundleMapLearner: 2x SAGEConv (mean) -> linear -> Cayley map
// bf16 MFMA pipeline: all GEMMs on matrix cores, all intermediates bf16,
// fp32 accumulation + fp32 bias/ReLU/Cayley.
// ---------------------------------------------------------------------------

#define WS_ALIGN(x) (((x) + 255) & ~size_t(255))

typedef __attribute__((ext_vector_type(8))) short short8;
typedef __attribute__((ext_vector_type(4))) float floatx4;

static __device__ __forceinline__ ushort f2b(float f) {
    unsigned u = __builtin_bit_cast(unsigned, f);
    u = (u + 0x7fffu + ((u >> 16) & 1u)) >> 16;   // RNE, finite inputs
    return (ushort)u;
}
static __device__ __forceinline__ float b2f(ushort h) {
    unsigned u = ((unsigned)h) << 16;
    return __builtin_bit_cast(float, u);
}

// ---------------- CSR build ----------------

__global__ void hist_kernel(const int* __restrict__ dst, int* __restrict__ deg, int E) {
    int e = blockIdx.x * blockDim.x + threadIdx.x;
    if (e < E) atomicAdd(&deg[dst[e]], 1);
}

__global__ void scan_kernel(const int* __restrict__ deg, int* __restrict__ rowptr, int n) {
    __shared__ int sh[1024];
    __shared__ int carry_s;
    int tid = threadIdx.x;
    if (tid == 0) carry_s = 0;
    __syncthreads();
    for (int base = 0; base < n; base += 1024) {
        int i = base + tid;
        int v = (i < n) ? deg[i] : 0;
        sh[tid] = v;
        __syncthreads();
        for (int off = 1; off < 1024; off <<= 1) {
            int t = (tid >= off) ? sh[tid - off] : 0;
            __syncthreads();
            sh[tid] += t;
            __syncthreads();
        }
        int incl = sh[tid];
        int carry = carry_s;
        if (i < n) rowptr[i] = carry + incl - v;   // exclusive
        __syncthreads();
        if (tid == 1023) carry_s = carry + incl;
        __syncthreads();
    }
    if (tid == 0) rowptr[n] = carry_s;
}

__global__ void scatter_kernel(const int* __restrict__ src, const int* __restrict__ dst,
                               const int* __restrict__ rowptr, int* __restrict__ cursor,
                               int* __restrict__ adj, int E) {
    int e = blockIdx.x * blockDim.x + threadIdx.x;
    if (e < E) {
        int d = dst[e];
        int p = atomicAdd(&cursor[d], 1);
        adj[rowptr[d] + p] = src[e];
    }
}

// ---------------- casts ----------------

__global__ void cast_kernel(const float* __restrict__ src, ushort* __restrict__ dst, int n8) {
    for (int i = blockIdx.x * blockDim.x + threadIdx.x; i < n8; i += gridDim.x * blockDim.x) {
        const float4* s4 = reinterpret_cast<const float4*>(src + (size_t)i * 8);
        float4 v0 = s4[0], v1 = s4[1];
        short8 o;
        o[0] = (short)f2b(v0.x); o[1] = (short)f2b(v0.y);
        o[2] = (short)f2b(v0.z); o[3] = (short)f2b(v0.w);
        o[4] = (short)f2b(v1.x); o[5] = (short)f2b(v1.y);
        o[6] = (short)f2b(v1.z); o[7] = (short)f2b(v1.w);
        *reinterpret_cast<short8*>(dst + (size_t)i * 8) = o;
    }
}

// Build concatenated bf16 weight matrices: Wc1 = [W1l;W1r] (512x512), Wc2 = [W2l;W2r] (256x256)
__global__ void build_wcat(const float* __restrict__ W1l, const float* __restrict__ W1r,
                           const float* __restrict__ W2l, const float* __restrict__ W2r,
                           ushort* __restrict__ Wc1, ushort* __restrict__ Wc2) {
    int idx = blockIdx.x * blockDim.x + threadIdx.x;
    const int n1 = (512 * 512) / 8;
    const int n2 = (256 * 256) / 8;
    const float* src;
    ushort* dst;
    if (idx < n1) {
        int e = idx * 8;
        int row = e >> 9, col = e & 511;
        src = (row < 256) ? &W1l[row * 512 + col] : &W1r[(row - 256) * 512 + col];
        dst = &Wc1[e];
    } else if (idx < n1 + n2) {
        int e = (idx - n1) * 8;
        int row = e >> 8, col = e & 255;
        src = (row < 128) ? &W2l[row * 256 + col] : &W2r[(row - 128) * 256 + col];
        dst = &Wc2[e];
    } else {
        return;
    }
    const float4* s4 = reinterpret_cast<const float4*>(src);
    float4 v0 = s4[0], v1 = s4[1];
    short8 o;
    o[0] = (short)f2b(v0.x); o[1] = (short)f2b(v0.y);
    o[2] = (short)f2b(v0.z); o[3] = (short)f2b(v0.w);
    o[4] = (short)f2b(v1.x); o[5] = (short)f2b(v1.y);
    o[6] = (short)f2b(v1.z); o[7] = (short)f2b(v1.w);
    *reinterpret_cast<short8*>(dst) = o;
}

// ---------------- bf16 MFMA GEMM: C = A @ B^T ----------------
// A [M,K] bf16 row-major, B [Ncols,K] bf16 row-major (weights), C [M,Ncols] bf16.
// 128x128 tile, BK=64, 4 waves (each 64x64), 16x16x32 MFMA.
// LDS tiles [128 rows][64 bf16] with XOR swizzle: in-row byte q holds element
// q ^ ((row&7)<<4). Staged via global_load_lds (linear dest, pre-swizzled src),
// read with the same XOR -> conflict-free-ish ds_read_b128 (rule #21 respected).

__global__ __launch_bounds__(256)
void gemm_bf16(const ushort* __restrict__ A, const ushort* __restrict__ B,
               ushort* __restrict__ C, int M, int K, int Ncols) {
    __shared__ ushort As[128 * 64];   // 16 KB
    __shared__ ushort Bs[128 * 64];   // 16 KB
    const int tid  = threadIdx.x;
    const int wave = tid >> 6;
    const int lane = tid & 63;
    const int row0 = blockIdx.y * 128;
    const int col0 = blockIdx.x * 128;
    const int wm = (wave & 1) * 64;
    const int wn = (wave >> 1) * 64;

    floatx4 acc[4][4];
#pragma unroll
    for (int i = 0; i < 4; ++i)
#pragma unroll
        for (int j = 0; j < 4; ++j)
            acc[i][j] = (floatx4){0.f, 0.f, 0.f, 0.f};

    const int rsub = lane >> 3;                        // row within 8-row chunk
    const int ksw  = ((lane & 7) * 16) ^ (rsub << 4);  // pre-swizzled byte-in-row

    for (int k0 = 0; k0 < K; k0 += 64) {
        // stage A tile: 16 chunks of 1KB (8 rows each); 4 per wave
#pragma unroll
        for (int i = 0; i < 4; ++i) {
            int chunk = wave * 4 + i;
            int r = chunk * 8 + rsub;
            int grow = row0 + r;
            if (grow >= M) grow = M - 1;               // clamp (stores guarded)
            const char* src = (const char*)(A + (size_t)grow * K + k0) + ksw;
            __builtin_amdgcn_global_load_lds(
                (const __attribute__((address_space(1))) unsigned int*)src,
                (__attribute__((address_space(3))) unsigned int*)(&As[chunk * 512]),
                16, 0, 0);
        }
#pragma unroll
        for (int i = 0; i < 4; ++i) {
            int chunk = wave * 4 + i;
            int r = chunk * 8 + rsub;
            int gcol = col0 + r;                       // Ncols % 128 == 0
            const char* src = (const char*)(B + (size_t)gcol * K + k0) + ksw;
            __builtin_amdgcn_global_load_lds(
                (const __attribute__((address_space(1))) unsigned int*)src,
                (__attribute__((address_space(3))) unsigned int*)(&Bs[chunk * 512]),
                16, 0, 0);
        }
        __syncthreads();

#pragma unroll
        for (int kk = 0; kk < 2; ++kk) {
            short8 af[4], bf[4];
            const int kb = (kk * 64 + ((lane >> 4) << 4)) ^ ((lane & 7) << 4);
#pragma unroll
            for (int im = 0; im < 4; ++im) {
                int r = wm + im * 16 + (lane & 15);
                af[im] = *reinterpret_cast<const short8*>((const char*)As + r * 128 + kb);
            }
#pragma unroll
            for (int in = 0; in < 4; ++in) {
                int r = wn + in * 16 + (lane & 15);
                bf[in] = *reinterpret_cast<const short8*>((const char*)Bs + r * 128 + kb);
            }
#pragma unroll
            for (int im = 0; im < 4; ++im)
#pragma unroll
                for (int in = 0; in < 4; ++in)
                    acc[im][in] = __builtin_amdgcn_mfma_f32_16x16x32_bf16(
                        af[im], bf[in], acc[im][in], 0, 0, 0);
        }
        __syncthreads();
    }

    // epilogue: C/D layout col=lane&15, row=(lane>>4)*4+reg (m89-verified)
#pragma unroll
    for (int im = 0; im < 4; ++im) {
#pragma unroll
        for (int reg = 0; reg < 4; ++reg) {
            int r = row0 + wm + im * 16 + ((lane >> 4) << 2) + reg;
            if (r < M) {
                size_t base = (size_t)r * Ncols + col0 + wn + (lane & 15);
#pragma unroll
                for (int in = 0; in < 4; ++in)
                    C[base + in * 16] = f2b(acc[im][in][reg]);
            }
        }
    }
}

// ---------------- aggregation: h = relu(mean_l + self_r + b), bf16 ----------------
// Y = [N, 2F] bf16: cols [0,F) = lin_l half, [F,2F) = lin_r half.

template <int VEC>
__global__ __launch_bounds__(256)
void aggregate_bf16(const ushort* __restrict__ Y, const float* __restrict__ bias,
                    const int* __restrict__ rowptr, const int* __restrict__ adj,
                    ushort* __restrict__ H, int n, int F) {
    int wave = threadIdx.x >> 6;
    int lane = threadIdx.x & 63;
    int node = blockIdx.x * 4 + wave;
    if (node >= n) return;
    int c = lane * VEC;
    int start = rowptr[node], end = rowptr[node + 1];
    const int twoF = 2 * F;
    float acc[VEC];
#pragma unroll
    for (int v = 0; v < VEC; ++v) acc[v] = 0.f;
    for (int e = start; e < end; ++e) {
        int s = adj[e];
        const ushort* row = &Y[(size_t)s * twoF + c];
        if constexpr (VEC == 4) {
            ushort4 r = *reinterpret_cast<const ushort4*>(row);
            acc[0] += b2f(r.x); acc[1] += b2f(r.y);
            acc[2] += b2f(r.z); acc[3] += b2f(r.w);
        } else {
            ushort2 r = *reinterpret_cast<const ushort2*>(row);
            acc[0] += b2f(r.x); acc[1] += b2f(r.y);
        }
    }
    int d = end - start;
    float inv = 1.0f / (float)(d > 0 ? d : 1);
    const ushort* self = &Y[(size_t)node * twoF + F + c];
    if constexpr (VEC == 4) {
        ushort4 sv = *reinterpret_cast<const ushort4*>(self);
        float4 bv = *reinterpret_cast<const float4*>(&bias[c]);
        ushort4 o;
        o.x = f2b(fmaxf(acc[0] * inv + b2f(sv.x) + bv.x, 0.f));
        o.y = f2b(fmaxf(acc[1] * inv + b2f(sv.y) + bv.y, 0.f));
        o.z = f2b(fmaxf(acc[2] * inv + b2f(sv.z) + bv.z, 0.f));
        o.w = f2b(fmaxf(acc[3] * inv + b2f(sv.w) + bv.w, 0.f));
        *reinterpret_cast<ushort4*>(&H[(size_t)node * F + c]) = o;
    } else {
        ushort2 sv = *reinterpret_cast<const ushort2*>(self);
        float2 bv = *reinterpret_cast<const float2*>(&bias[c]);
        ushort2 o;
        o.x = f2b(fmaxf(acc[0] * inv + b2f(sv.x) + bv.x, 0.f));
        o.y = f2b(fmaxf(acc[1] * inv + b2f(sv.y) + bv.y, 0.f));
        *reinterpret_cast<ushort2*>(&H[(size_t)node * F + c]) = o;
    }
}

// ---------------- final: params + Cayley ----------------

__global__ __launch_bounds__(256)
void final_kernel(const ushort* __restrict__ H2, const float* __restrict__ Wp,
                  const float* __restrict__ bp, float* __restrict__ Out, int n) {
    __shared__ float WpS[28 * 128];
    __shared__ float bpS[28];
    for (int t = threadIdx.x; t < 28 * 128; t += 256) WpS[t] = Wp[t];
    if (threadIdx.x < 28) bpS[threadIdx.x] = bp[threadIdx.x];
    __syncthreads();

    int i = blockIdx.x * blockDim.x + threadIdx.x;
    if (i >= n) return;

    float p[28];
#pragma unroll
    for (int j = 0; j < 28; ++j) p[j] = bpS[j];
    const short8* hp = reinterpret_cast<const short8*>(&H2[(size_t)i * 128]);
#pragma unroll
    for (int q = 0; q < 16; ++q) {
        short8 hv = hp[q];
        float h[8];
#pragma unroll
        for (int t = 0; t < 8; ++t) h[t] = b2f((ushort)hv[t]);
#pragma unroll
        for (int j = 0; j < 28; ++j) {
            const float* w = &WpS[j * 128 + 8 * q];
            float s = 0.f;
#pragma unroll
            for (int t = 0; t < 8; ++t) s += h[t] * w[t];
            p[j] += s;
        }
    }

    // M = I - A, B = I + A; unpivoted Gauss-Jordan (sym(I-A)=I SPD, pivots >= 1)
    float M_[8][8], B_[8][8];
#pragma unroll
    for (int r = 0; r < 8; ++r)
#pragma unroll
        for (int c = 0; c < 8; ++c) {
            M_[r][c] = (r == c) ? 1.f : 0.f;
            B_[r][c] = (r == c) ? 1.f : 0.f;
        }
    {
        int idx = 0;
#pragma unroll
        for (int r = 0; r < 8; ++r)
#pragma unroll
            for (int c = r + 1; c < 8; ++c) {
                float a = p[idx++];
                M_[r][c] -= a;  M_[c][r] += a;
                B_[r][c] += a;  B_[c][r] -= a;
            }
    }
#pragma unroll
    for (int col = 0; col < 8; ++col) {
        float inv = 1.0f / M_[col][col];
#pragma unroll
        for (int c = 0; c < 8; ++c) { M_[col][c] *= inv; B_[col][c] *= inv; }
#pragma unroll
        for (int r = 0; r < 8; ++r) {
            if (r == col) continue;
            float f = M_[r][col];
#pragma unroll
            for (int c = 0; c < 8; ++c) {
                M_[r][c] -= f * M_[col][c];
                B_[r][c] -= f * B_[col][c];
            }
        }
    }
    float* out = &Out[(size_t)i * 64];
#pragma unroll
    for (int r = 0; r < 8; ++r) {
        float4 o0 = make_float4(B_[r][0], B_[r][1], B_[r][2], B_[r][3]);
        float4 o1 = make_float4(B_[r][4], B_[r][5], B_[r][6], B_[r][7]);
        *reinterpret_cast<float4*>(&out[r * 8 + 0]) = o0;
        *reinterpret_cast<float4*>(&out[r * 8 + 4]) = o1;
    }
}

// ---------------------------------------------------------------------------

extern "C" void kernel_launch(void* const* d_in, const int* in_sizes, int n_in,
                              void* d_out, int out_size, void* d_ws, size_t ws_size,
                              hipStream_t stream) {
    const float* x   = (const float*)d_in[0];
    const int*   ei  = (const int*)d_in[1];
    const float* W1l = (const float*)d_in[2];
    const float* b1  = (const float*)d_in[3];
    const float* W1r = (const float*)d_in[4];
    const float* W2l = (const float*)d_in[5];
    const float* b2  = (const float*)d_in[6];
    const float* W2r = (const float*)d_in[7];
    const float* Wp  = (const float*)d_in[8];
    const float* bp  = (const float*)d_in[9];
    float* out = (float*)d_out;

    const int IN_DIM = 512;
    const int N = in_sizes[0] / IN_DIM;   // 50000
    const int E = in_sizes[1] / 2;        // 800000

    // workspace layout (reuse: xb->z, Y->h2)
    char* ws = (char*)d_ws;
    size_t off = 0;
    int* deg      = (int*)(ws + off); off = WS_ALIGN(off + (size_t)N * 4);
    int* rowptr   = (int*)(ws + off); off = WS_ALIGN(off + (size_t)(N + 1) * 4);
    int* cursor   = (int*)(ws + off); off = WS_ALIGN(off + (size_t)N * 4);
    int* adj      = (int*)(ws + off); off = WS_ALIGN(off + (size_t)E * 4);
    ushort* xb    = (ushort*)(ws + off); off = WS_ALIGN(off + (size_t)N * 512 * 2);
    ushort* Y     = (ushort*)(ws + off); off = WS_ALIGN(off + (size_t)N * 512 * 2);
    ushort* h1    = (ushort*)(ws + off); off = WS_ALIGN(off + (size_t)N * 256 * 2);
    ushort* Wc1   = (ushort*)(ws + off); off = WS_ALIGN(off + (size_t)512 * 512 * 2);
    ushort* Wc2   = (ushort*)(ws + off); off = WS_ALIGN(off + (size_t)256 * 256 * 2);

    const int* src = ei;
    const int* dst = ei + E;

    hipMemsetAsync(deg, 0, (size_t)N * 4, stream);
    hipMemsetAsync(cursor, 0, (size_t)N * 4, stream);

    int eb = (E + 255) / 256;
    hist_kernel<<<eb, 256, 0, stream>>>(dst, deg, E);
    scan_kernel<<<1, 1024, 0, stream>>>(deg, rowptr, N);
    scatter_kernel<<<eb, 256, 0, stream>>>(src, dst, rowptr, cursor, adj, E);

    cast_kernel<<<1024, 256, 0, stream>>>(x, xb, N * 512 / 8);
    build_wcat<<<((512 * 512 + 256 * 256) / 8 + 255) / 256, 256, 0, stream>>>(
        W1l, W1r, W2l, W2r, Wc1, Wc2);

    int gm = (N + 127) / 128;   // 391

    // layer 1: Y = xb @ Wc1^T   [N,512] bf16
    gemm_bf16<<<dim3(4, gm), 256, 0, stream>>>(xb, Wc1, Y, N, 512, 512);
    // h1 = relu(mean + self + b1)  [N,256] bf16
    aggregate_bf16<4><<<(N + 3) / 4, 256, 0, stream>>>(Y, b1, rowptr, adj, h1, N, 256);

    // layer 2: z = h1 @ Wc2^T   [N,256] bf16 (reuse xb)
    ushort* zb = xb;
    gemm_bf16<<<dim3(2, gm), 256, 0, stream>>>(h1, Wc2, zb, N, 256, 256);
    // h2  [N,128] bf16 (reuse Y)
    ushort* h2 = Y;
    aggregate_bf16<2><<<(N + 3) / 4, 256, 0, stream>>>(zb, b2, rowptr, adj, h2, N, 128);

    // params + Cayley -> out [N,8,8] fp32
    final_kernel<<<(N + 255) / 256, 256, 0, stream>>>(h2, Wp, bp, out, N);
}

// Round 3
// 388.802 us; speedup vs baseline: 2.2702x; 1.2345x over previous
//
#include <hip/hip_runtime.h>
#include <hip/hip_bf16.h>

// ---------------------------------------------------------------------------
// InductiveBundleMapLearner: 2x SAGEConv (mean) -> linear -> Cayley map
// bf16 MFMA pipeline; latency-optimized CSR aggregation (4-deep gather MLP).
// ---------------------------------------------------------------------------

#define WS_ALIGN(x) (((x) + 255) & ~size_t(255))

typedef __attribute__((ext_vector_type(8))) short short8;
typedef __attribute__((ext_vector_type(4))) float floatx4;

static __device__ __forceinline__ ushort f2b(float f) {
    unsigned u = __builtin_bit_cast(unsigned, f);
    u = (u + 0x7fffu + ((u >> 16) & 1u)) >> 16;   // RNE, finite inputs
    return (ushort)u;
}
static __device__ __forceinline__ float b2f(ushort h) {
    unsigned u = ((unsigned)h) << 16;
    return __builtin_bit_cast(float, u);
}

// ---------------- CSR build ----------------

__global__ void hist_kernel(const int* __restrict__ dst, int* __restrict__ deg, int E) {
    int e = blockIdx.x * blockDim.x + threadIdx.x;
    if (e < E) atomicAdd(&deg[dst[e]], 1);
}

// single-block scan: thread-serial chunks + one 1024-wide Hillis-Steele pass
__global__ void scan_kernel(const int* __restrict__ deg, int* __restrict__ rowptr, int n) {
    __shared__ int part[1024];
    const int tid = threadIdx.x;
    const int chunk = (n + 1023) >> 10;
    const int s0 = tid * chunk;
    const int s1 = min(s0 + chunk, n);
    int sum = 0;
    for (int i = s0; i < s1; ++i) sum += deg[i];
    part[tid] = sum;
    __syncthreads();
    for (int off = 1; off < 1024; off <<= 1) {
        int t = (tid >= off) ? part[tid - off] : 0;
        __syncthreads();
        part[tid] += t;
        __syncthreads();
    }
    int pre = (tid > 0) ? part[tid - 1] : 0;   // exclusive prefix of this chunk
    for (int i = s0; i < s1; ++i) { rowptr[i] = pre; pre += deg[i]; }
    if (tid == 1023) rowptr[n] = part[1023];
}

__global__ void scatter_kernel(const int* __restrict__ src, const int* __restrict__ dst,
                               const int* __restrict__ rowptr, int* __restrict__ cursor,
                               int* __restrict__ adj, int E) {
    int e = blockIdx.x * blockDim.x + threadIdx.x;
    if (e < E) {
        int d = dst[e];
        int p = atomicAdd(&cursor[d], 1);
        adj[rowptr[d] + p] = src[e];
    }
}

// ---------------- casts ----------------

__global__ void cast_kernel(const float* __restrict__ src, ushort* __restrict__ dst, int n8) {
    for (int i = blockIdx.x * blockDim.x + threadIdx.x; i < n8; i += gridDim.x * blockDim.x) {
        const float4* s4 = reinterpret_cast<const float4*>(src + (size_t)i * 8);
        float4 v0 = s4[0], v1 = s4[1];
        short8 o;
        o[0] = (short)f2b(v0.x); o[1] = (short)f2b(v0.y);
        o[2] = (short)f2b(v0.z); o[3] = (short)f2b(v0.w);
        o[4] = (short)f2b(v1.x); o[5] = (short)f2b(v1.y);
        o[6] = (short)f2b(v1.z); o[7] = (short)f2b(v1.w);
        *reinterpret_cast<short8*>(dst + (size_t)i * 8) = o;
    }
}

// Wc1 = [W1l;W1r] (512x512), Wc2 = [W2l;W2r] (256x256), bf16
__global__ void build_wcat(const float* __restrict__ W1l, const float* __restrict__ W1r,
                           const float* __restrict__ W2l, const float* __restrict__ W2r,
                           ushort* __restrict__ Wc1, ushort* __restrict__ Wc2) {
    int idx = blockIdx.x * blockDim.x + threadIdx.x;
    const int n1 = (512 * 512) / 8;
    const int n2 = (256 * 256) / 8;
    const float* src;
    ushort* dst;
    if (idx < n1) {
        int e = idx * 8;
        int row = e >> 9, col = e & 511;
        src = (row < 256) ? &W1l[row * 512 + col] : &W1r[(row - 256) * 512 + col];
        dst = &Wc1[e];
    } else if (idx < n1 + n2) {
        int e = (idx - n1) * 8;
        int row = e >> 8, col = e & 255;
        src = (row < 128) ? &W2l[row * 256 + col] : &W2r[(row - 128) * 256 + col];
        dst = &Wc2[e];
    } else {
        return;
    }
    const float4* s4 = reinterpret_cast<const float4*>(src);
    float4 v0 = s4[0], v1 = s4[1];
    short8 o;
    o[0] = (short)f2b(v0.x); o[1] = (short)f2b(v0.y);
    o[2] = (short)f2b(v0.z); o[3] = (short)f2b(v0.w);
    o[4] = (short)f2b(v1.x); o[5] = (short)f2b(v1.y);
    o[6] = (short)f2b(v1.z); o[7] = (short)f2b(v1.w);
    *reinterpret_cast<short8*>(dst) = o;
}

// ---------------- bf16 MFMA GEMM: C = A @ B^T ----------------
// 128x128 tile, BK=64, 4 waves, 16x16x32 MFMA, global_load_lds + XOR swizzle.

__global__ __launch_bounds__(256)
void gemm_bf16(const ushort* __restrict__ A, const ushort* __restrict__ B,
               ushort* __restrict__ C, int M, int K, int Ncols) {
    __shared__ ushort As[128 * 64];   // 16 KB
    __shared__ ushort Bs[128 * 64];   // 16 KB
    const int tid  = threadIdx.x;
    const int wave = tid >> 6;
    const int lane = tid & 63;
    const int row0 = blockIdx.y * 128;
    const int col0 = blockIdx.x * 128;
    const int wm = (wave & 1) * 64;
    const int wn = (wave >> 1) * 64;

    floatx4 acc[4][4];
#pragma unroll
    for (int i = 0; i < 4; ++i)
#pragma unroll
        for (int j = 0; j < 4; ++j)
            acc[i][j] = (floatx4){0.f, 0.f, 0.f, 0.f};

    const int rsub = lane >> 3;                        // row within 8-row chunk
    const int ksw  = ((lane & 7) * 16) ^ (rsub << 4);  // pre-swizzled byte-in-row

    for (int k0 = 0; k0 < K; k0 += 64) {
#pragma unroll
        for (int i = 0; i < 4; ++i) {
            int chunk = wave * 4 + i;
            int r = chunk * 8 + rsub;
            int grow = row0 + r;
            if (grow >= M) grow = M - 1;               // clamp (stores guarded)
            const char* src = (const char*)(A + (size_t)grow * K + k0) + ksw;
            __builtin_amdgcn_global_load_lds(
                (const __attribute__((address_space(1))) unsigned int*)src,
                (__attribute__((address_space(3))) unsigned int*)(&As[chunk * 512]),
                16, 0, 0);
        }
#pragma unroll
        for (int i = 0; i < 4; ++i) {
            int chunk = wave * 4 + i;
            int r = chunk * 8 + rsub;
            int gcol = col0 + r;                       // Ncols % 128 == 0
            const char* src = (const char*)(B + (size_t)gcol * K + k0) + ksw;
            __builtin_amdgcn_global_load_lds(
                (const __attribute__((address_space(1))) unsigned int*)src,
                (__attribute__((address_space(3))) unsigned int*)(&Bs[chunk * 512]),
                16, 0, 0);
        }
        __syncthreads();

#pragma unroll
        for (int kk = 0; kk < 2; ++kk) {
            short8 af[4], bf[4];
            const int kb = (kk * 64 + ((lane >> 4) << 4)) ^ ((lane & 7) << 4);
#pragma unroll
            for (int im = 0; im < 4; ++im) {
                int r = wm + im * 16 + (lane & 15);
                af[im] = *reinterpret_cast<const short8*>((const char*)As + r * 128 + kb);
            }
#pragma unroll
            for (int in = 0; in < 4; ++in) {
                int r = wn + in * 16 + (lane & 15);
                bf[in] = *reinterpret_cast<const short8*>((const char*)Bs + r * 128 + kb);
            }
#pragma unroll
            for (int im = 0; im < 4; ++im)
#pragma unroll
                for (int in = 0; in < 4; ++in)
                    acc[im][in] = __builtin_amdgcn_mfma_f32_16x16x32_bf16(
                        af[im], bf[in], acc[im][in], 0, 0, 0);
        }
        __syncthreads();
    }

#pragma unroll
    for (int im = 0; im < 4; ++im) {
#pragma unroll
        for (int reg = 0; reg < 4; ++reg) {
            int r = row0 + wm + im * 16 + ((lane >> 4) << 2) + reg;
            if (r < M) {
                size_t base = (size_t)r * Ncols + col0 + wn + (lane & 15);
#pragma unroll
                for (int in = 0; in < 4; ++in)
                    C[base + in * 16] = f2b(acc[im][in][reg]);
            }
        }
    }
}

// ---------------- aggregation: h = relu(mean_l + self_r + b), bf16 ----------------
// Y = [N, 2F]: cols [0,F) lin_l, [F,2F) lin_r. LPN lanes per node, VEC=4 ch/lane.
// Edge loop unrolled x4: 4 independent row-gathers in flight per lane group.

template <int LPN>
__global__ __launch_bounds__(256)
void aggregate_bf16(const ushort* __restrict__ Y, const float* __restrict__ bias,
                    const int* __restrict__ rowptr, const int* __restrict__ adj,
                    ushort* __restrict__ H, int n) {
    constexpr int F = LPN * 4;
    const int grp = threadIdx.x / LPN;
    const int sub = threadIdx.x % LPN;
    const int node = blockIdx.x * (256 / LPN) + grp;
    if (node >= n) return;
    const int c = sub * 4;
    const int start = rowptr[node], end = rowptr[node + 1];
    const int twoF = 2 * F;

    float a0 = 0.f, a1 = 0.f, a2 = 0.f, a3 = 0.f;
    int e = start;
    for (; e + 4 <= end; e += 4) {
        int s0 = adj[e + 0], s1 = adj[e + 1], s2 = adj[e + 2], s3 = adj[e + 3];
        ushort4 r0 = *reinterpret_cast<const ushort4*>(&Y[(size_t)s0 * twoF + c]);
        ushort4 r1 = *reinterpret_cast<const ushort4*>(&Y[(size_t)s1 * twoF + c]);
        ushort4 r2 = *reinterpret_cast<const ushort4*>(&Y[(size_t)s2 * twoF + c]);
        ushort4 r3 = *reinterpret_cast<const ushort4*>(&Y[(size_t)s3 * twoF + c]);
        a0 += (b2f(r0.x) + b2f(r1.x)) + (b2f(r2.x) + b2f(r3.x));
        a1 += (b2f(r0.y) + b2f(r1.y)) + (b2f(r2.y) + b2f(r3.y));
        a2 += (b2f(r0.z) + b2f(r1.z)) + (b2f(r2.z) + b2f(r3.z));
        a3 += (b2f(r0.w) + b2f(r1.w)) + (b2f(r2.w) + b2f(r3.w));
    }
    for (; e < end; ++e) {
        int s = adj[e];
        ushort4 r = *reinterpret_cast<const ushort4*>(&Y[(size_t)s * twoF + c]);
        a0 += b2f(r.x); a1 += b2f(r.y); a2 += b2f(r.z); a3 += b2f(r.w);
    }

    const int d = end - start;
    const float inv = 1.0f / (float)(d > 0 ? d : 1);
    ushort4 sv = *reinterpret_cast<const ushort4*>(&Y[(size_t)node * twoF + F + c]);
    float4 bv = *reinterpret_cast<const float4*>(&bias[c]);
    ushort4 o;
    o.x = f2b(fmaxf(a0 * inv + b2f(sv.x) + bv.x, 0.f));
    o.y = f2b(fmaxf(a1 * inv + b2f(sv.y) + bv.y, 0.f));
    o.z = f2b(fmaxf(a2 * inv + b2f(sv.z) + bv.z, 0.f));
    o.w = f2b(fmaxf(a3 * inv + b2f(sv.w) + bv.w, 0.f));
    *reinterpret_cast<ushort4*>(&H[(size_t)node * F + c]) = o;
}

// ---------------- final: params + Cayley ----------------

__global__ __launch_bounds__(256)
void final_kernel(const ushort* __restrict__ H2, const float* __restrict__ Wp,
                  const float* __restrict__ bp, float* __restrict__ Out, int n) {
    __shared__ float WpS[28 * 128];
    __shared__ float bpS[28];
    for (int t = threadIdx.x; t < 28 * 128; t += 256) WpS[t] = Wp[t];
    if (threadIdx.x < 28) bpS[threadIdx.x] = bp[threadIdx.x];
    __syncthreads();

    int i = blockIdx.x * blockDim.x + threadIdx.x;
    if (i >= n) return;

    float p[28];
#pragma unroll
    for (int j = 0; j < 28; ++j) p[j] = bpS[j];
    const short8* hp = reinterpret_cast<const short8*>(&H2[(size_t)i * 128]);
#pragma unroll
    for (int q = 0; q < 16; ++q) {
        short8 hv = hp[q];
        float h[8];
#pragma unroll
        for (int t = 0; t < 8; ++t) h[t] = b2f((ushort)hv[t]);
#pragma unroll
        for (int j = 0; j < 28; ++j) {
            const float* w = &WpS[j * 128 + 8 * q];
            float s = 0.f;
#pragma unroll
            for (int t = 0; t < 8; ++t) s += h[t] * w[t];
            p[j] += s;
        }
    }

    // M = I - A, B = I + A; unpivoted Gauss-Jordan (sym(I-A)=I SPD, pivots >= 1)
    float M_[8][8], B_[8][8];
#pragma unroll
    for (int r = 0; r < 8; ++r)
#pragma unroll
        for (int c = 0; c < 8; ++c) {
            M_[r][c] = (r == c) ? 1.f : 0.f;
            B_[r][c] = (r == c) ? 1.f : 0.f;
        }
    {
        int idx = 0;
#pragma unroll
        for (int r = 0; r < 8; ++r)
#pragma unroll
            for (int c = r + 1; c < 8; ++c) {
                float a = p[idx++];
                M_[r][c] -= a;  M_[c][r] += a;
                B_[r][c] += a;  B_[c][r] -= a;
            }
    }
#pragma unroll
    for (int col = 0; col < 8; ++col) {
        float inv = 1.0f / M_[col][col];
#pragma unroll
        for (int c = 0; c < 8; ++c) { M_[col][c] *= inv; B_[col][c] *= inv; }
#pragma unroll
        for (int r = 0; r < 8; ++r) {
            if (r == col) continue;
            float f = M_[r][col];
#pragma unroll
            for (int c = 0; c < 8; ++c) {
                M_[r][c] -= f * M_[col][c];
                B_[r][c] -= f * B_[col][c];
            }
        }
    }
    float* out = &Out[(size_t)i * 64];
#pragma unroll
    for (int r = 0; r < 8; ++r) {
        float4 o0 = make_float4(B_[r][0], B_[r][1], B_[r][2], B_[r][3]);
        float4 o1 = make_float4(B_[r][4], B_[r][5], B_[r][6], B_[r][7]);
        *reinterpret_cast<float4*>(&out[r * 8 + 0]) = o0;
        *reinterpret_cast<float4*>(&out[r * 8 + 4]) = o1;
    }
}

// ---------------------------------------------------------------------------

extern "C" void kernel_launch(void* const* d_in, const int* in_sizes, int n_in,
                              void* d_out, int out_size, void* d_ws, size_t ws_size,
                              hipStream_t stream) {
    const float* x   = (const float*)d_in[0];
    const int*   ei  = (const int*)d_in[1];
    const float* W1l = (const float*)d_in[2];
    const float* b1  = (const float*)d_in[3];
    const float* W1r = (const float*)d_in[4];
    const float* W2l = (const float*)d_in[5];
    const float* b2  = (const float*)d_in[6];
    const float* W2r = (const float*)d_in[7];
    const float* Wp  = (const float*)d_in[8];
    const float* bp  = (const float*)d_in[9];
    float* out = (float*)d_out;

    const int IN_DIM = 512;
    const int N = in_sizes[0] / IN_DIM;   // 50000
    const int E = in_sizes[1] / 2;        // 800000

    char* ws = (char*)d_ws;
    size_t off = 0;
    int* deg      = (int*)(ws + off); off = WS_ALIGN(off + (size_t)N * 4);
    int* rowptr   = (int*)(ws + off); off = WS_ALIGN(off + (size_t)(N + 1) * 4);
    int* cursor   = (int*)(ws + off); off = WS_ALIGN(off + (size_t)N * 4);
    int* adj      = (int*)(ws + off); off = WS_ALIGN(off + (size_t)E * 4);
    ushort* xb    = (ushort*)(ws + off); off = WS_ALIGN(off + (size_t)N * 512 * 2);
    ushort* Y     = (ushort*)(ws + off); off = WS_ALIGN(off + (size_t)N * 512 * 2);
    ushort* h1    = (ushort*)(ws + off); off = WS_ALIGN(off + (size_t)N * 256 * 2);
    ushort* Wc1   = (ushort*)(ws + off); off = WS_ALIGN(off + (size_t)512 * 512 * 2);
    ushort* Wc2   = (ushort*)(ws + off); off = WS_ALIGN(off + (size_t)256 * 256 * 2);

    const int* src = ei;
    const int* dst = ei + E;

    hipMemsetAsync(deg, 0, (size_t)N * 4, stream);
    hipMemsetAsync(cursor, 0, (size_t)N * 4, stream);

    int eb = (E + 255) / 256;
    hist_kernel<<<eb, 256, 0, stream>>>(dst, deg, E);
    scan_kernel<<<1, 1024, 0, stream>>>(deg, rowptr, N);
    scatter_kernel<<<eb, 256, 0, stream>>>(src, dst, rowptr, cursor, adj, E);

    cast_kernel<<<1024, 256, 0, stream>>>(x, xb, N * 512 / 8);
    build_wcat<<<((512 * 512 + 256 * 256) / 8 + 255) / 256, 256, 0, stream>>>(
        W1l, W1r, W2l, W2r, Wc1, Wc2);

    int gm = (N + 127) / 128;   // 391

    // layer 1: Y = xb @ Wc1^T   [N,512] bf16
    gemm_bf16<<<dim3(4, gm), 256, 0, stream>>>(xb, Wc1, Y, N, 512, 512);
    // h1 = relu(mean + self + b1)  [N,256] bf16 (64 lanes/node)
    aggregate_bf16<64><<<(N + 3) / 4, 256, 0, stream>>>(Y, b1, rowptr, adj, h1, N);

    // layer 2: z = h1 @ Wc2^T   [N,256] bf16 (reuse xb)
    ushort* zb = xb;
    gemm_bf16<<<dim3(2, gm), 256, 0, stream>>>(h1, Wc2, zb, N, 256, 256);
    // h2  [N,128] bf16 (reuse Y; 32 lanes/node)
    ushort* h2 = Y;
    aggregate_bf16<32><<<(N + 7) / 8, 256, 0, stream>>>(zb, b2, rowptr, adj, h2, N);

    // params + Cayley -> out [N,8,8] fp32
    final_kernel<<<(N + 255) / 256, 256, 0, stream>>>(h2, Wp, bp, out, N);
}

// Round 4
// 324.851 us; speedup vs baseline: 2.7171x; 1.1969x over previous
//
#include <hip/hip_runtime.h>
#include <hip/hip_bf16.h>

// ---------------------------------------------------------------------------
// InductiveBundleMapLearner: 2x SAGEConv (mean) -> linear -> Cayley map
// bf16 MFMA pipeline; 4-deep gather MLP aggregation; 3-phase parallel scan.
// ---------------------------------------------------------------------------

#define WS_ALIGN(x) (((x) + 255) & ~size_t(255))

typedef __attribute__((ext_vector_type(8))) short short8;
typedef __attribute__((ext_vector_type(4))) float floatx4;

static __device__ __forceinline__ ushort f2b(float f) {
    unsigned u = __builtin_bit_cast(unsigned, f);
    u = (u + 0x7fffu + ((u >> 16) & 1u)) >> 16;   // RNE, finite inputs
    return (ushort)u;
}
static __device__ __forceinline__ float b2f(ushort h) {
    unsigned u = ((unsigned)h) << 16;
    return __builtin_bit_cast(float, u);
}

// ---------------- CSR build ----------------

__global__ void hist_kernel(const int* __restrict__ dst, int* __restrict__ deg, int E) {
    int e = blockIdx.x * blockDim.x + threadIdx.x;
    if (e < E) atomicAdd(&deg[dst[e]], 1);
}

// 3-phase parallel exclusive scan of deg[N] -> rowptr[N+1]
// phase 1: per-block (1024 elems) sums
__global__ __launch_bounds__(256)
void scan_phase1(const int* __restrict__ deg, int* __restrict__ bsum, int n) {
    __shared__ int red[256];
    const int t = threadIdx.x;
    const int i = blockIdx.x * 1024 + t * 4;
    int s = 0;
    if (i + 4 <= n) {
        int4 v = *reinterpret_cast<const int4*>(&deg[i]);
        s = v.x + v.y + v.z + v.w;
    } else {
        for (int k = i; k < n; ++k) s += deg[k];
    }
    red[t] = s;
    __syncthreads();
#pragma unroll
    for (int off = 128; off > 0; off >>= 1) {
        if (t < off) red[t] += red[t + off];
        __syncthreads();
    }
    if (t == 0) bsum[blockIdx.x] = red[0];
}

// phase 2: single block scans the <=256 partials -> exclusive; writes rowptr[n]
__global__ __launch_bounds__(256)
void scan_phase2(int* __restrict__ bsum, int* __restrict__ rowptr, int nb, int n) {
    __shared__ int sh[256];
    const int t = threadIdx.x;
    int orig = (t < nb) ? bsum[t] : 0;
    sh[t] = orig;
    __syncthreads();
#pragma unroll
    for (int off = 1; off < 256; off <<= 1) {
        int v = (t >= off) ? sh[t - off] : 0;
        __syncthreads();
        sh[t] += v;
        __syncthreads();
    }
    if (t < nb) bsum[t] = sh[t] - orig;          // exclusive block offsets
    if (t == 255) rowptr[n] = sh[255];           // total
}

// phase 3: per-block exclusive scan + block offset -> rowptr[0..n)
__global__ __launch_bounds__(256)
void scan_phase3(const int* __restrict__ deg, const int* __restrict__ bsum,
                 int* __restrict__ rowptr, int n) {
    __shared__ int red[256];
    const int t = threadIdx.x;
    const int i = blockIdx.x * 1024 + t * 4;
    int v0 = 0, v1 = 0, v2 = 0, v3 = 0;
    if (i + 4 <= n) {
        int4 v = *reinterpret_cast<const int4*>(&deg[i]);
        v0 = v.x; v1 = v.y; v2 = v.z; v3 = v.w;
    } else {
        if (i     < n) v0 = deg[i];
        if (i + 1 < n) v1 = deg[i + 1];
        if (i + 2 < n) v2 = deg[i + 2];
        if (i + 3 < n) v3 = deg[i + 3];
    }
    int s = v0 + v1 + v2 + v3;
    red[t] = s;
    __syncthreads();
#pragma unroll
    for (int off = 1; off < 256; off <<= 1) {
        int u = (t >= off) ? red[t - off] : 0;
        __syncthreads();
        red[t] += u;
        __syncthreads();
    }
    int pre = bsum[blockIdx.x] + red[t] - s;     // exclusive prefix for this thread
    if (i + 4 <= n) {
        int4 o;
        o.x = pre; o.y = pre + v0; o.z = pre + v0 + v1; o.w = pre + v0 + v1 + v2;
        *reinterpret_cast<int4*>(&rowptr[i]) = o;
    } else {
        if (i     < n) rowptr[i]     = pre;
        if (i + 1 < n) rowptr[i + 1] = pre + v0;
        if (i + 2 < n) rowptr[i + 2] = pre + v0 + v1;
        if (i + 3 < n) rowptr[i + 3] = pre + v0 + v1 + v2;
    }
}

__global__ void scatter_kernel(const int* __restrict__ src, const int* __restrict__ dst,
                               const int* __restrict__ rowptr, int* __restrict__ cursor,
                               int* __restrict__ adj, int E) {
    int e = blockIdx.x * blockDim.x + threadIdx.x;
    if (e < E) {
        int d = dst[e];
        int p = atomicAdd(&cursor[d], 1);
        adj[rowptr[d] + p] = src[e];
    }
}

// ---------------- casts ----------------

__global__ void cast_kernel(const float* __restrict__ src, ushort* __restrict__ dst, int n8) {
    for (int i = blockIdx.x * blockDim.x + threadIdx.x; i < n8; i += gridDim.x * blockDim.x) {
        const float4* s4 = reinterpret_cast<const float4*>(src + (size_t)i * 8);
        float4 v0 = s4[0], v1 = s4[1];
        short8 o;
        o[0] = (short)f2b(v0.x); o[1] = (short)f2b(v0.y);
        o[2] = (short)f2b(v0.z); o[3] = (short)f2b(v0.w);
        o[4] = (short)f2b(v1.x); o[5] = (short)f2b(v1.y);
        o[6] = (short)f2b(v1.z); o[7] = (short)f2b(v1.w);
        *reinterpret_cast<short8*>(dst + (size_t)i * 8) = o;
    }
}

// Wc1 = [W1l;W1r] (512x512), Wc2 = [W2l;W2r] (256x256), bf16
__global__ void build_wcat(const float* __restrict__ W1l, const float* __restrict__ W1r,
                           const float* __restrict__ W2l, const float* __restrict__ W2r,
                           ushort* __restrict__ Wc1, ushort* __restrict__ Wc2) {
    int idx = blockIdx.x * blockDim.x + threadIdx.x;
    const int n1 = (512 * 512) / 8;
    const int n2 = (256 * 256) / 8;
    const float* src;
    ushort* dst;
    if (idx < n1) {
        int e = idx * 8;
        int row = e >> 9, col = e & 511;
        src = (row < 256) ? &W1l[row * 512 + col] : &W1r[(row - 256) * 512 + col];
        dst = &Wc1[e];
    } else if (idx < n1 + n2) {
        int e = (idx - n1) * 8;
        int row = e >> 8, col = e & 255;
        src = (row < 128) ? &W2l[row * 256 + col] : &W2r[(row - 128) * 256 + col];
        dst = &Wc2[e];
    } else {
        return;
    }
    const float4* s4 = reinterpret_cast<const float4*>(src);
    float4 v0 = s4[0], v1 = s4[1];
    short8 o;
    o[0] = (short)f2b(v0.x); o[1] = (short)f2b(v0.y);
    o[2] = (short)f2b(v0.z); o[3] = (short)f2b(v0.w);
    o[4] = (short)f2b(v1.x); o[5] = (short)f2b(v1.y);
    o[6] = (short)f2b(v1.z); o[7] = (short)f2b(v1.w);
    *reinterpret_cast<short8*>(dst) = o;
}

// ---------------- bf16 MFMA GEMM: C = A @ B^T ----------------
// 128x128 tile, BK=64, 4 waves, 16x16x32 MFMA, global_load_lds + XOR swizzle.

__global__ __launch_bounds__(256)
void gemm_bf16(const ushort* __restrict__ A, const ushort* __restrict__ B,
               ushort* __restrict__ C, int M, int K, int Ncols) {
    __shared__ ushort As[128 * 64];   // 16 KB
    __shared__ ushort Bs[128 * 64];   // 16 KB
    const int tid  = threadIdx.x;
    const int wave = tid >> 6;
    const int lane = tid & 63;
    const int row0 = blockIdx.y * 128;
    const int col0 = blockIdx.x * 128;
    const int wm = (wave & 1) * 64;
    const int wn = (wave >> 1) * 64;

    floatx4 acc[4][4];
#pragma unroll
    for (int i = 0; i < 4; ++i)
#pragma unroll
        for (int j = 0; j < 4; ++j)
            acc[i][j] = (floatx4){0.f, 0.f, 0.f, 0.f};

    const int rsub = lane >> 3;                        // row within 8-row chunk
    const int ksw  = ((lane & 7) * 16) ^ (rsub << 4);  // pre-swizzled byte-in-row

    for (int k0 = 0; k0 < K; k0 += 64) {
#pragma unroll
        for (int i = 0; i < 4; ++i) {
            int chunk = wave * 4 + i;
            int r = chunk * 8 + rsub;
            int grow = row0 + r;
            if (grow >= M) grow = M - 1;               // clamp (stores guarded)
            const char* src = (const char*)(A + (size_t)grow * K + k0) + ksw;
            __builtin_amdgcn_global_load_lds(
                (const __attribute__((address_space(1))) unsigned int*)src,
                (__attribute__((address_space(3))) unsigned int*)(&As[chunk * 512]),
                16, 0, 0);
        }
#pragma unroll
        for (int i = 0; i < 4; ++i) {
            int chunk = wave * 4 + i;
            int r = chunk * 8 + rsub;
            int gcol = col0 + r;                       // Ncols % 128 == 0
            const char* src = (const char*)(B + (size_t)gcol * K + k0) + ksw;
            __builtin_amdgcn_global_load_lds(
                (const __attribute__((address_space(1))) unsigned int*)src,
                (__attribute__((address_space(3))) unsigned int*)(&Bs[chunk * 512]),
                16, 0, 0);
        }
        __syncthreads();

#pragma unroll
        for (int kk = 0; kk < 2; ++kk) {
            short8 af[4], bf[4];
            const int kb = (kk * 64 + ((lane >> 4) << 4)) ^ ((lane & 7) << 4);
#pragma unroll
            for (int im = 0; im < 4; ++im) {
                int r = wm + im * 16 + (lane & 15);
                af[im] = *reinterpret_cast<const short8*>((const char*)As + r * 128 + kb);
            }
#pragma unroll
            for (int in = 0; in < 4; ++in) {
                int r = wn + in * 16 + (lane & 15);
                bf[in] = *reinterpret_cast<const short8*>((const char*)Bs + r * 128 + kb);
            }
#pragma unroll
            for (int im = 0; im < 4; ++im)
#pragma unroll
                for (int in = 0; in < 4; ++in)
                    acc[im][in] = __builtin_amdgcn_mfma_f32_16x16x32_bf16(
                        af[im], bf[in], acc[im][in], 0, 0, 0);
        }
        __syncthreads();
    }

#pragma unroll
    for (int im = 0; im < 4; ++im) {
#pragma unroll
        for (int reg = 0; reg < 4; ++reg) {
            int r = row0 + wm + im * 16 + ((lane >> 4) << 2) + reg;
            if (r < M) {
                size_t base = (size_t)r * Ncols + col0 + wn + (lane & 15);
#pragma unroll
                for (int in = 0; in < 4; ++in)
                    C[base + in * 16] = f2b(acc[im][in][reg]);
            }
        }
    }
}

// ---------------- aggregation: h = relu(mean_l + self_r + b), bf16 ----------------
// Y = [N, 2F]: cols [0,F) lin_l, [F,2F) lin_r. LPN lanes per node, 4 ch/lane.
// Edge loop unrolled x4: 4 independent row-gathers in flight.

template <int LPN>
__global__ __launch_bounds__(256)
void aggregate_bf16(const ushort* __restrict__ Y, const float* __restrict__ bias,
                    const int* __restrict__ rowptr, const int* __restrict__ adj,
                    ushort* __restrict__ H, int n) {
    constexpr int F = LPN * 4;
    const int grp = threadIdx.x / LPN;
    const int sub = threadIdx.x % LPN;
    const int node = blockIdx.x * (256 / LPN) + grp;
    if (node >= n) return;
    const int c = sub * 4;
    const int start = rowptr[node], end = rowptr[node + 1];
    const int twoF = 2 * F;

    float a0 = 0.f, a1 = 0.f, a2 = 0.f, a3 = 0.f;
    int e = start;
    for (; e + 4 <= end; e += 4) {
        int s0 = adj[e + 0], s1 = adj[e + 1], s2 = adj[e + 2], s3 = adj[e + 3];
        ushort4 r0 = *reinterpret_cast<const ushort4*>(&Y[(size_t)s0 * twoF + c]);
        ushort4 r1 = *reinterpret_cast<const ushort4*>(&Y[(size_t)s1 * twoF + c]);
        ushort4 r2 = *reinterpret_cast<const ushort4*>(&Y[(size_t)s2 * twoF + c]);
        ushort4 r3 = *reinterpret_cast<const ushort4*>(&Y[(size_t)s3 * twoF + c]);
        a0 += (b2f(r0.x) + b2f(r1.x)) + (b2f(r2.x) + b2f(r3.x));
        a1 += (b2f(r0.y) + b2f(r1.y)) + (b2f(r2.y) + b2f(r3.y));
        a2 += (b2f(r0.z) + b2f(r1.z)) + (b2f(r2.z) + b2f(r3.z));
        a3 += (b2f(r0.w) + b2f(r1.w)) + (b2f(r2.w) + b2f(r3.w));
    }
    for (; e < end; ++e) {
        int s = adj[e];
        ushort4 r = *reinterpret_cast<const ushort4*>(&Y[(size_t)s * twoF + c]);
        a0 += b2f(r.x); a1 += b2f(r.y); a2 += b2f(r.z); a3 += b2f(r.w);
    }

    const int d = end - start;
    const float inv = 1.0f / (float)(d > 0 ? d : 1);
    ushort4 sv = *reinterpret_cast<const ushort4*>(&Y[(size_t)node * twoF + F + c]);
    float4 bv = *reinterpret_cast<const float4*>(&bias[c]);
    ushort4 o;
    o.x = f2b(fmaxf(a0 * inv + b2f(sv.x) + bv.x, 0.f));
    o.y = f2b(fmaxf(a1 * inv + b2f(sv.y) + bv.y, 0.f));
    o.z = f2b(fmaxf(a2 * inv + b2f(sv.z) + bv.z, 0.f));
    o.w = f2b(fmaxf(a3 * inv + b2f(sv.w) + bv.w, 0.f));
    *reinterpret_cast<ushort4*>(&H[(size_t)node * F + c]) = o;
}

// ---------------- final: params + Cayley ----------------

__global__ __launch_bounds__(256)
void final_kernel(const ushort* __restrict__ H2, const float* __restrict__ Wp,
                  const float* __restrict__ bp, float* __restrict__ Out, int n) {
    __shared__ float WpS[28 * 128];
    __shared__ float bpS[28];
    for (int t = threadIdx.x; t < 28 * 128; t += 256) WpS[t] = Wp[t];
    if (threadIdx.x < 28) bpS[threadIdx.x] = bp[threadIdx.x];
    __syncthreads();

    int i = blockIdx.x * blockDim.x + threadIdx.x;
    if (i >= n) return;

    float p[28];
#pragma unroll
    for (int j = 0; j < 28; ++j) p[j] = bpS[j];
    const short8* hp = reinterpret_cast<const short8*>(&H2[(size_t)i * 128]);
#pragma unroll
    for (int q = 0; q < 16; ++q) {
        short8 hv = hp[q];
        float h[8];
#pragma unroll
        for (int t = 0; t < 8; ++t) h[t] = b2f((ushort)hv[t]);
#pragma unroll
        for (int j = 0; j < 28; ++j) {
            const float* w = &WpS[j * 128 + 8 * q];
            float s = 0.f;
#pragma unroll
            for (int t = 0; t < 8; ++t) s += h[t] * w[t];
            p[j] += s;
        }
    }

    // M = I - A, B = I + A; unpivoted Gauss-Jordan (sym(I-A)=I SPD, pivots >= 1)
    float M_[8][8], B_[8][8];
#pragma unroll
    for (int r = 0; r < 8; ++r)
#pragma unroll
        for (int c = 0; c < 8; ++c) {
            M_[r][c] = (r == c) ? 1.f : 0.f;
            B_[r][c] = (r == c) ? 1.f : 0.f;
        }
    {
        int idx = 0;
#pragma unroll
        for (int r = 0; r < 8; ++r)
#pragma unroll
            for (int c = r + 1; c < 8; ++c) {
                float a = p[idx++];
                M_[r][c] -= a;  M_[c][r] += a;
                B_[r][c] += a;  B_[c][r] -= a;
            }
    }
#pragma unroll
    for (int col = 0; col < 8; ++col) {
        float inv = 1.0f / M_[col][col];
#pragma unroll
        for (int c = 0; c < 8; ++c) { M_[col][c] *= inv; B_[col][c] *= inv; }
#pragma unroll
        for (int r = 0; r < 8; ++r) {
            if (r == col) continue;
            float f = M_[r][col];
#pragma unroll
            for (int c = 0; c < 8; ++c) {
                M_[r][c] -= f * M_[col][c];
                B_[r][c] -= f * B_[col][c];
            }
        }
    }
    float* out = &Out[(size_t)i * 64];
#pragma unroll
    for (int r = 0; r < 8; ++r) {
        float4 o0 = make_float4(B_[r][0], B_[r][1], B_[r][2], B_[r][3]);
        float4 o1 = make_float4(B_[r][4], B_[r][5], B_[r][6], B_[r][7]);
        *reinterpret_cast<float4*>(&out[r * 8 + 0]) = o0;
        *reinterpret_cast<float4*>(&out[r * 8 + 4]) = o1;
    }
}

// ---------------------------------------------------------------------------

extern "C" void kernel_launch(void* const* d_in, const int* in_sizes, int n_in,
                              void* d_out, int out_size, void* d_ws, size_t ws_size,
                              hipStream_t stream) {
    const float* x   = (const float*)d_in[0];
    const int*   ei  = (const int*)d_in[1];
    const float* W1l = (const float*)d_in[2];
    const float* b1  = (const float*)d_in[3];
    const float* W1r = (const float*)d_in[4];
    const float* W2l = (const float*)d_in[5];
    const float* b2  = (const float*)d_in[6];
    const float* W2r = (const float*)d_in[7];
    const float* Wp  = (const float*)d_in[8];
    const float* bp  = (const float*)d_in[9];
    float* out = (float*)d_out;

    const int IN_DIM = 512;
    const int N = in_sizes[0] / IN_DIM;   // 50000
    const int E = in_sizes[1] / 2;        // 800000

    char* ws = (char*)d_ws;
    size_t off = 0;
    int* deg      = (int*)(ws + off); off = WS_ALIGN(off + (size_t)N * 4);
    int* rowptr   = (int*)(ws + off); off = WS_ALIGN(off + (size_t)(N + 1) * 4);
    int* cursor   = (int*)(ws + off); off = WS_ALIGN(off + (size_t)N * 4);
    int* bsum     = (int*)(ws + off); off = WS_ALIGN(off + (size_t)256 * 4);
    int* adj      = (int*)(ws + off); off = WS_ALIGN(off + (size_t)E * 4);
    ushort* xb    = (ushort*)(ws + off); off = WS_ALIGN(off + (size_t)N * 512 * 2);
    ushort* Y     = (ushort*)(ws + off); off = WS_ALIGN(off + (size_t)N * 512 * 2);
    ushort* h1    = (ushort*)(ws + off); off = WS_ALIGN(off + (size_t)N * 256 * 2);
    ushort* Wc1   = (ushort*)(ws + off); off = WS_ALIGN(off + (size_t)512 * 512 * 2);
    ushort* Wc2   = (ushort*)(ws + off); off = WS_ALIGN(off + (size_t)256 * 256 * 2);

    const int* src = ei;
    const int* dst = ei + E;

    hipMemsetAsync(deg, 0, (size_t)N * 4, stream);
    hipMemsetAsync(cursor, 0, (size_t)N * 4, stream);

    int eb = (E + 255) / 256;
    int nb = (N + 1023) / 1024;   // 49 <= 256
    hist_kernel<<<eb, 256, 0, stream>>>(dst, deg, E);
    scan_phase1<<<nb, 256, 0, stream>>>(deg, bsum, N);
    scan_phase2<<<1, 256, 0, stream>>>(bsum, rowptr, nb, N);
    scan_phase3<<<nb, 256, 0, stream>>>(deg, bsum, rowptr, N);
    scatter_kernel<<<eb, 256, 0, stream>>>(src, dst, rowptr, cursor, adj, E);

    cast_kernel<<<1024, 256, 0, stream>>>(x, xb, N * 512 / 8);
    build_wcat<<<((512 * 512 + 256 * 256) / 8 + 255) / 256, 256, 0, stream>>>(
        W1l, W1r, W2l, W2r, Wc1, Wc2);

    int gm = (N + 127) / 128;   // 391

    // layer 1: Y = xb @ Wc1^T   [N,512] bf16
    gemm_bf16<<<dim3(4, gm), 256, 0, stream>>>(xb, Wc1, Y, N, 512, 512);
    // h1 = relu(mean + self + b1)  [N,256] bf16 (64 lanes/node)
    aggregate_bf16<64><<<(N + 3) / 4, 256, 0, stream>>>(Y, b1, rowptr, adj, h1, N);

    // layer 2: z = h1 @ Wc2^T   [N,256] bf16 (reuse xb)
    ushort* zb = xb;
    gemm_bf16<<<dim3(2, gm), 256, 0, stream>>>(h1, Wc2, zb, N, 256, 256);
    // h2  [N,128] bf16 (reuse Y; 32 lanes/node)
    ushort* h2 = Y;
    aggregate_bf16<32><<<(N + 7) / 8, 256, 0, stream>>>(zb, b2, rowptr, adj, h2, N);

    // params + Cayley -> out [N,8,8] fp32
    final_kernel<<<(N + 255) / 256, 256, 0, stream>>>(h2, Wp, bp, out, N);
}

// Round 5
// 301.503 us; speedup vs baseline: 2.9275x; 1.0774x over previous
//
#include <hip/hip_runtime.h>
#include <hip/hip_bf16.h>

// ---------------------------------------------------------------------------
// InductiveBundleMapLearner: 2x SAGEConv (mean) -> linear -> Cayley map
// bf16 MFMA pipeline; split Yl/Yr for L3-friendly gathers; wide params kernel.
// ---------------------------------------------------------------------------

#define WS_ALIGN(x) (((x) + 255) & ~size_t(255))

typedef __attribute__((ext_vector_type(8))) short short8;
typedef __attribute__((ext_vector_type(4))) float floatx4;

static __device__ __forceinline__ ushort f2b(float f) {
    unsigned u = __builtin_bit_cast(unsigned, f);
    u = (u + 0x7fffu + ((u >> 16) & 1u)) >> 16;   // RNE, finite inputs
    return (ushort)u;
}
static __device__ __forceinline__ float b2f(ushort h) {
    unsigned u = ((unsigned)h) << 16;
    return __builtin_bit_cast(float, u);
}

// ---------------- CSR build ----------------

__global__ void hist_kernel(const int* __restrict__ dst, int* __restrict__ deg, int E) {
    int e = blockIdx.x * blockDim.x + threadIdx.x;
    if (e < E) atomicAdd(&deg[dst[e]], 1);
}

__global__ __launch_bounds__(256)
void scan_phase1(const int* __restrict__ deg, int* __restrict__ bsum, int n) {
    __shared__ int red[256];
    const int t = threadIdx.x;
    const int i = blockIdx.x * 1024 + t * 4;
    int s = 0;
    if (i + 4 <= n) {
        int4 v = *reinterpret_cast<const int4*>(&deg[i]);
        s = v.x + v.y + v.z + v.w;
    } else {
        for (int k = i; k < n; ++k) s += deg[k];
    }
    red[t] = s;
    __syncthreads();
#pragma unroll
    for (int off = 128; off > 0; off >>= 1) {
        if (t < off) red[t] += red[t + off];
        __syncthreads();
    }
    if (t == 0) bsum[blockIdx.x] = red[0];
}

__global__ __launch_bounds__(256)
void scan_phase2(int* __restrict__ bsum, int* __restrict__ rowptr, int nb, int n) {
    __shared__ int sh[256];
    const int t = threadIdx.x;
    int orig = (t < nb) ? bsum[t] : 0;
    sh[t] = orig;
    __syncthreads();
#pragma unroll
    for (int off = 1; off < 256; off <<= 1) {
        int v = (t >= off) ? sh[t - off] : 0;
        __syncthreads();
        sh[t] += v;
        __syncthreads();
    }
    if (t < nb) bsum[t] = sh[t] - orig;          // exclusive block offsets
    if (t == 255) rowptr[n] = sh[255];           // total
}

__global__ __launch_bounds__(256)
void scan_phase3(const int* __restrict__ deg, const int* __restrict__ bsum,
                 int* __restrict__ rowptr, int n) {
    __shared__ int red[256];
    const int t = threadIdx.x;
    const int i = blockIdx.x * 1024 + t * 4;
    int v0 = 0, v1 = 0, v2 = 0, v3 = 0;
    if (i + 4 <= n) {
        int4 v = *reinterpret_cast<const int4*>(&deg[i]);
        v0 = v.x; v1 = v.y; v2 = v.z; v3 = v.w;
    } else {
        if (i     < n) v0 = deg[i];
        if (i + 1 < n) v1 = deg[i + 1];
        if (i + 2 < n) v2 = deg[i + 2];
        if (i + 3 < n) v3 = deg[i + 3];
    }
    int s = v0 + v1 + v2 + v3;
    red[t] = s;
    __syncthreads();
#pragma unroll
    for (int off = 1; off < 256; off <<= 1) {
        int u = (t >= off) ? red[t - off] : 0;
        __syncthreads();
        red[t] += u;
        __syncthreads();
    }
    int pre = bsum[blockIdx.x] + red[t] - s;
    if (i + 4 <= n) {
        int4 o;
        o.x = pre; o.y = pre + v0; o.z = pre + v0 + v1; o.w = pre + v0 + v1 + v2;
        *reinterpret_cast<int4*>(&rowptr[i]) = o;
    } else {
        if (i     < n) rowptr[i]     = pre;
        if (i + 1 < n) rowptr[i + 1] = pre + v0;
        if (i + 2 < n) rowptr[i + 2] = pre + v0 + v1;
        if (i + 3 < n) rowptr[i + 3] = pre + v0 + v1 + v2;
    }
}

__global__ void scatter_kernel(const int* __restrict__ src, const int* __restrict__ dst,
                               const int* __restrict__ rowptr, int* __restrict__ cursor,
                               int* __restrict__ adj, int E) {
    int e = blockIdx.x * blockDim.x + threadIdx.x;
    if (e < E) {
        int d = dst[e];
        int p = atomicAdd(&cursor[d], 1);
        adj[rowptr[d] + p] = src[e];
    }
}

// ---------------- casts ----------------

__global__ void cast_kernel(const float* __restrict__ src, ushort* __restrict__ dst, int n8) {
    for (int i = blockIdx.x * blockDim.x + threadIdx.x; i < n8; i += gridDim.x * blockDim.x) {
        const float4* s4 = reinterpret_cast<const float4*>(src + (size_t)i * 8);
        float4 v0 = s4[0], v1 = s4[1];
        short8 o;
        o[0] = (short)f2b(v0.x); o[1] = (short)f2b(v0.y);
        o[2] = (short)f2b(v0.z); o[3] = (short)f2b(v0.w);
        o[4] = (short)f2b(v1.x); o[5] = (short)f2b(v1.y);
        o[6] = (short)f2b(v1.z); o[7] = (short)f2b(v1.w);
        *reinterpret_cast<short8*>(dst + (size_t)i * 8) = o;
    }
}

// Wc1 = [W1l;W1r] (512x512), Wc2 = [W2l;W2r] (256x256), bf16
__global__ void build_wcat(const float* __restrict__ W1l, const float* __restrict__ W1r,
                           const float* __restrict__ W2l, const float* __restrict__ W2r,
                           ushort* __restrict__ Wc1, ushort* __restrict__ Wc2) {
    int idx = blockIdx.x * blockDim.x + threadIdx.x;
    const int n1 = (512 * 512) / 8;
    const int n2 = (256 * 256) / 8;
    const float* src;
    ushort* dst;
    if (idx < n1) {
        int e = idx * 8;
        int row = e >> 9, col = e & 511;
        src = (row < 256) ? &W1l[row * 512 + col] : &W1r[(row - 256) * 512 + col];
        dst = &Wc1[e];
    } else if (idx < n1 + n2) {
        int e = (idx - n1) * 8;
        int row = e >> 8, col = e & 255;
        src = (row < 128) ? &W2l[row * 256 + col] : &W2r[(row - 128) * 256 + col];
        dst = &Wc2[e];
    } else {
        return;
    }
    const float4* s4 = reinterpret_cast<const float4*>(src);
    float4 v0 = s4[0], v1 = s4[1];
    short8 o;
    o[0] = (short)f2b(v0.x); o[1] = (short)f2b(v0.y);
    o[2] = (short)f2b(v0.z); o[3] = (short)f2b(v0.w);
    o[4] = (short)f2b(v1.x); o[5] = (short)f2b(v1.y);
    o[6] = (short)f2b(v1.z); o[7] = (short)f2b(v1.w);
    *reinterpret_cast<short8*>(dst) = o;
}

// ---------------- bf16 MFMA GEMM: [Cl|Cr] = A @ B^T ----------------
// 128x128 tile, BK=64, 4 waves, 16x16x32 MFMA, global_load_lds + XOR swizzle.
// Output columns [0,S) -> Cl (pitch S), [S,Ncols) -> Cr (pitch Ncols-S == S).
// S and Ncols are multiples of 128 so the split is uniform per block.

__global__ __launch_bounds__(256)
void gemm_bf16(const ushort* __restrict__ A, const ushort* __restrict__ B,
               ushort* __restrict__ Cl, ushort* __restrict__ Cr,
               int M, int K, int Ncols, int S) {
    __shared__ ushort As[128 * 64];   // 16 KB
    __shared__ ushort Bs[128 * 64];   // 16 KB
    const int tid  = threadIdx.x;
    const int wave = tid >> 6;
    const int lane = tid & 63;
    const int row0 = blockIdx.y * 128;
    const int col0 = blockIdx.x * 128;
    const int wm = (wave & 1) * 64;
    const int wn = (wave >> 1) * 64;

    floatx4 acc[4][4];
#pragma unroll
    for (int i = 0; i < 4; ++i)
#pragma unroll
        for (int j = 0; j < 4; ++j)
            acc[i][j] = (floatx4){0.f, 0.f, 0.f, 0.f};

    const int rsub = lane >> 3;                        // row within 8-row chunk
    const int ksw  = ((lane & 7) * 16) ^ (rsub << 4);  // pre-swizzled byte-in-row

    for (int k0 = 0; k0 < K; k0 += 64) {
#pragma unroll
        for (int i = 0; i < 4; ++i) {
            int chunk = wave * 4 + i;
            int r = chunk * 8 + rsub;
            int grow = row0 + r;
            if (grow >= M) grow = M - 1;               // clamp (stores guarded)
            const char* src = (const char*)(A + (size_t)grow * K + k0) + ksw;
            __builtin_amdgcn_global_load_lds(
                (const __attribute__((address_space(1))) unsigned int*)src,
                (__attribute__((address_space(3))) unsigned int*)(&As[chunk * 512]),
                16, 0, 0);
        }
#pragma unroll
        for (int i = 0; i < 4; ++i) {
            int chunk = wave * 4 + i;
            int r = chunk * 8 + rsub;
            int gcol = col0 + r;                       // Ncols % 128 == 0
            const char* src = (const char*)(B + (size_t)gcol * K + k0) + ksw;
            __builtin_amdgcn_global_load_lds(
                (const __attribute__((address_space(1))) unsigned int*)src,
                (__attribute__((address_space(3))) unsigned int*)(&Bs[chunk * 512]),
                16, 0, 0);
        }
        __syncthreads();

#pragma unroll
        for (int kk = 0; kk < 2; ++kk) {
            short8 af[4], bf[4];
            const int kb = (kk * 64 + ((lane >> 4) << 4)) ^ ((lane & 7) << 4);
#pragma unroll
            for (int im = 0; im < 4; ++im) {
                int r = wm + im * 16 + (lane & 15);
                af[im] = *reinterpret_cast<const short8*>((const char*)As + r * 128 + kb);
            }
#pragma unroll
            for (int in = 0; in < 4; ++in) {
                int r = wn + in * 16 + (lane & 15);
                bf[in] = *reinterpret_cast<const short8*>((const char*)Bs + r * 128 + kb);
            }
#pragma unroll
            for (int im = 0; im < 4; ++im)
#pragma unroll
                for (int in = 0; in < 4; ++in)
                    acc[im][in] = __builtin_amdgcn_mfma_f32_16x16x32_bf16(
                        af[im], bf[in], acc[im][in], 0, 0, 0);
        }
        __syncthreads();
    }

    ushort* Cbase = (col0 < S) ? Cl : Cr;
    const int cb = (col0 < S) ? col0 : col0 - S;
#pragma unroll
    for (int im = 0; im < 4; ++im) {
#pragma unroll
        for (int reg = 0; reg < 4; ++reg) {
            int r = row0 + wm + im * 16 + ((lane >> 4) << 2) + reg;
            if (r < M) {
                size_t base = (size_t)r * S + cb + wn + (lane & 15);
#pragma unroll
                for (int in = 0; in < 4; ++in)
                    Cbase[base + in * 16] = f2b(acc[im][in][reg]);
            }
        }
    }
}

// ---------------- aggregation: h = relu(mean_l + self_r + b), bf16 ----------------
// Yl/Yr = [N, F] separate buffers (L3-friendly contiguous gather rows).
// LPN lanes per node, 4 ch/lane; edge loop unrolled x4 for MLP.

template <int LPN>
__global__ __launch_bounds__(256)
void aggregate_bf16(const ushort* __restrict__ Yl, const ushort* __restrict__ Yr,
                    const float* __restrict__ bias,
                    const int* __restrict__ rowptr, const int* __restrict__ adj,
                    ushort* __restrict__ H, int n) {
    constexpr int F = LPN * 4;
    const int grp = threadIdx.x / LPN;
    const int sub = threadIdx.x % LPN;
    const int node = blockIdx.x * (256 / LPN) + grp;
    if (node >= n) return;
    const int c = sub * 4;
    const int start = rowptr[node], end = rowptr[node + 1];

    float a0 = 0.f, a1 = 0.f, a2 = 0.f, a3 = 0.f;
    int e = start;
    for (; e + 4 <= end; e += 4) {
        int s0 = adj[e + 0], s1 = adj[e + 1], s2 = adj[e + 2], s3 = adj[e + 3];
        ushort4 r0 = *reinterpret_cast<const ushort4*>(&Yl[(size_t)s0 * F + c]);
        ushort4 r1 = *reinterpret_cast<const ushort4*>(&Yl[(size_t)s1 * F + c]);
        ushort4 r2 = *reinterpret_cast<const ushort4*>(&Yl[(size_t)s2 * F + c]);
        ushort4 r3 = *reinterpret_cast<const ushort4*>(&Yl[(size_t)s3 * F + c]);
        a0 += (b2f(r0.x) + b2f(r1.x)) + (b2f(r2.x) + b2f(r3.x));
        a1 += (b2f(r0.y) + b2f(r1.y)) + (b2f(r2.y) + b2f(r3.y));
        a2 += (b2f(r0.z) + b2f(r1.z)) + (b2f(r2.z) + b2f(r3.z));
        a3 += (b2f(r0.w) + b2f(r1.w)) + (b2f(r2.w) + b2f(r3.w));
    }
    for (; e < end; ++e) {
        int s = adj[e];
        ushort4 r = *reinterpret_cast<const ushort4*>(&Yl[(size_t)s * F + c]);
        a0 += b2f(r.x); a1 += b2f(r.y); a2 += b2f(r.z); a3 += b2f(r.w);
    }

    const int d = end - start;
    const float inv = 1.0f / (float)(d > 0 ? d : 1);
    ushort4 sv = *reinterpret_cast<const ushort4*>(&Yr[(size_t)node * F + c]);
    float4 bv = *reinterpret_cast<const float4*>(&bias[c]);
    ushort4 o;
    o.x = f2b(fmaxf(a0 * inv + b2f(sv.x) + bv.x, 0.f));
    o.y = f2b(fmaxf(a1 * inv + b2f(sv.y) + bv.y, 0.f));
    o.z = f2b(fmaxf(a2 * inv + b2f(sv.z) + bv.z, 0.f));
    o.w = f2b(fmaxf(a3 * inv + b2f(sv.w) + bv.w, 0.f));
    *reinterpret_cast<ushort4*>(&H[(size_t)node * F + c]) = o;
}

// ---------------- params: p = h2 @ Wp^T + bp -> P[N,32] ----------------
// 8 lanes/node; lane l owns params {l, l+8, l+16, l+24} and loops all 128 ch.
// No cross-lane reduce. WpS pitch 132 words -> lane word-stride 132*l == bank
// stride 4*l mod 32 -> 8 disjoint 4-bank spans per float4 read: conflict-free.

__global__ __launch_bounds__(256)
void params_kernel(const ushort* __restrict__ H2, const float* __restrict__ Wp,
                   const float* __restrict__ bp, float* __restrict__ P, int n) {
    __shared__ float WpS[32 * 132];
    __shared__ float bpS[32];
    for (int t = threadIdx.x; t < 32 * 132; t += 256) WpS[t] = 0.f;
    if (threadIdx.x < 32) bpS[threadIdx.x] = (threadIdx.x < 28) ? bp[threadIdx.x] : 0.f;
    __syncthreads();
    for (int t = threadIdx.x; t < 28 * 128; t += 256) {
        int r = t >> 7, c = t & 127;
        WpS[r * 132 + c] = Wp[t];
    }
    __syncthreads();

    const int node = blockIdx.x * 32 + (threadIdx.x >> 3);
    const int l = threadIdx.x & 7;
    if (node >= n) return;

    short8 h8[16];
    const short8* hp = reinterpret_cast<const short8*>(&H2[(size_t)node * 128]);
#pragma unroll
    for (int q = 0; q < 16; ++q) h8[q] = hp[q];

    float acc0 = bpS[l], acc1 = bpS[l + 8], acc2 = bpS[l + 16], acc3 = bpS[l + 24];
#pragma unroll
    for (int q = 0; q < 32; ++q) {
        float h0 = b2f((ushort)h8[q >> 1][(q & 1) * 4 + 0]);
        float h1 = b2f((ushort)h8[q >> 1][(q & 1) * 4 + 1]);
        float h2 = b2f((ushort)h8[q >> 1][(q & 1) * 4 + 2]);
        float h3 = b2f((ushort)h8[q >> 1][(q & 1) * 4 + 3]);
        float4 w0 = *reinterpret_cast<const float4*>(&WpS[(l +  0) * 132 + 4 * q]);
        float4 w1 = *reinterpret_cast<const float4*>(&WpS[(l +  8) * 132 + 4 * q]);
        float4 w2 = *reinterpret_cast<const float4*>(&WpS[(l + 16) * 132 + 4 * q]);
        float4 w3 = *reinterpret_cast<const float4*>(&WpS[(l + 24) * 132 + 4 * q]);
        acc0 += h0 * w0.x + h1 * w0.y + h2 * w0.z + h3 * w0.w;
        acc1 += h0 * w1.x + h1 * w1.y + h2 * w1.z + h3 * w1.w;
        acc2 += h0 * w2.x + h1 * w2.y + h2 * w2.z + h3 * w2.w;
        acc3 += h0 * w3.x + h1 * w3.y + h2 * w3.z + h3 * w3.w;
    }
    float* pout = &P[(size_t)node * 32];
    pout[l]      = acc0;
    pout[l + 8]  = acc1;
    pout[l + 16] = acc2;
    pout[l + 24] = acc3;
}

// ---------------- Cayley: O = (I-A)^{-1}(I+A) ----------------
// Unpivoted Gauss-Jordan (sym(I-A)=I SPD -> pivots >= 1), all static indices.

__global__ __launch_bounds__(256)
void cayley_kernel(const float* __restrict__ P, float* __restrict__ Out, int n) {
    int i = blockIdx.x * blockDim.x + threadIdx.x;
    if (i >= n) return;
    float p[28];
    const float4* pp = reinterpret_cast<const float4*>(&P[(size_t)i * 32]);
#pragma unroll
    for (int q = 0; q < 7; ++q) {
        float4 v = pp[q];
        p[4 * q + 0] = v.x; p[4 * q + 1] = v.y;
        p[4 * q + 2] = v.z; p[4 * q + 3] = v.w;
    }

    float M_[8][8], B_[8][8];
#pragma unroll
    for (int r = 0; r < 8; ++r)
#pragma unroll
        for (int c = 0; c < 8; ++c) {
            M_[r][c] = (r == c) ? 1.f : 0.f;
            B_[r][c] = (r == c) ? 1.f : 0.f;
        }
    {
        int idx = 0;
#pragma unroll
        for (int r = 0; r < 8; ++r)
#pragma unroll
            for (int c = r + 1; c < 8; ++c) {
                float a = p[idx++];
                M_[r][c] -= a;  M_[c][r] += a;
                B_[r][c] += a;  B_[c][r] -= a;
            }
    }
#pragma unroll
    for (int col = 0; col < 8; ++col) {
        float inv = 1.0f / M_[col][col];
#pragma unroll
        for (int c = 0; c < 8; ++c) { M_[col][c] *= inv; B_[col][c] *= inv; }
#pragma unroll
        for (int r = 0; r < 8; ++r) {
            if (r == col) continue;
            float f = M_[r][col];
#pragma unroll
            for (int c = 0; c < 8; ++c) {
                M_[r][c] -= f * M_[col][c];
                B_[r][c] -= f * B_[col][c];
            }
        }
    }
    float* out = &Out[(size_t)i * 64];
#pragma unroll
    for (int r = 0; r < 8; ++r) {
        float4 o0 = make_float4(B_[r][0], B_[r][1], B_[r][2], B_[r][3]);
        float4 o1 = make_float4(B_[r][4], B_[r][5], B_[r][6], B_[r][7]);
        *reinterpret_cast<float4*>(&out[r * 8 + 0]) = o0;
        *reinterpret_cast<float4*>(&out[r * 8 + 4]) = o1;
    }
}

// ---------------------------------------------------------------------------

extern "C" void kernel_launch(void* const* d_in, const int* in_sizes, int n_in,
                              void* d_out, int out_size, void* d_ws, size_t ws_size,
                              hipStream_t stream) {
    const float* x   = (const float*)d_in[0];
    const int*   ei  = (const int*)d_in[1];
    const float* W1l = (const float*)d_in[2];
    const float* b1  = (const float*)d_in[3];
    const float* W1r = (const float*)d_in[4];
    const float* W2l = (const float*)d_in[5];
    const float* b2  = (const float*)d_in[6];
    const float* W2r = (const float*)d_in[7];
    const float* Wp  = (const float*)d_in[8];
    const float* bp  = (const float*)d_in[9];
    float* out = (float*)d_out;

    const int IN_DIM = 512;
    const int N = in_sizes[0] / IN_DIM;   // 50000
    const int E = in_sizes[1] / 2;        // 800000

    char* ws = (char*)d_ws;
    size_t off = 0;
    int* deg      = (int*)(ws + off); off = WS_ALIGN(off + (size_t)N * 4);
    int* rowptr   = (int*)(ws + off); off = WS_ALIGN(off + (size_t)(N + 1) * 4);
    int* cursor   = (int*)(ws + off); off = WS_ALIGN(off + (size_t)N * 4);
    int* bsum     = (int*)(ws + off); off = WS_ALIGN(off + (size_t)256 * 4);
    int* adj      = (int*)(ws + off); off = WS_ALIGN(off + (size_t)E * 4);
    ushort* xb    = (ushort*)(ws + off); off = WS_ALIGN(off + (size_t)N * 512 * 2);
    ushort* Yl    = (ushort*)(ws + off); off = WS_ALIGN(off + (size_t)N * 256 * 2);
    ushort* Yr    = (ushort*)(ws + off); off = WS_ALIGN(off + (size_t)N * 256 * 2);
    ushort* h1    = (ushort*)(ws + off); off = WS_ALIGN(off + (size_t)N * 256 * 2);
    ushort* Wc1   = (ushort*)(ws + off); off = WS_ALIGN(off + (size_t)512 * 512 * 2);
    ushort* Wc2   = (ushort*)(ws + off); off = WS_ALIGN(off + (size_t)256 * 256 * 2);
    float*  Pp    = (float*)(ws + off);  off = WS_ALIGN(off + (size_t)N * 32 * 4);

    const int* src = ei;
    const int* dst = ei + E;

    hipMemsetAsync(deg, 0, (size_t)N * 4, stream);
    hipMemsetAsync(cursor, 0, (size_t)N * 4, stream);

    int eb = (E + 255) / 256;
    int nb = (N + 1023) / 1024;   // <= 256
    hist_kernel<<<eb, 256, 0, stream>>>(dst, deg, E);
    scan_phase1<<<nb, 256, 0, stream>>>(deg, bsum, N);
    scan_phase2<<<1, 256, 0, stream>>>(bsum, rowptr, nb, N);
    scan_phase3<<<nb, 256, 0, stream>>>(deg, bsum, rowptr, N);
    scatter_kernel<<<eb, 256, 0, stream>>>(src, dst, rowptr, cursor, adj, E);

    cast_kernel<<<1024, 256, 0, stream>>>(x, xb, N * 512 / 8);
    build_wcat<<<((512 * 512 + 256 * 256) / 8 + 255) / 256, 256, 0, stream>>>(
        W1l, W1r, W2l, W2r, Wc1, Wc2);

    int gm = (N + 127) / 128;   // 391

    // layer 1: [Yl|Yr] = xb @ Wc1^T   ([N,256] each, bf16)
    gemm_bf16<<<dim3(4, gm), 256, 0, stream>>>(xb, Wc1, Yl, Yr, N, 512, 512, 256);
    // h1 = relu(mean + self + b1)  [N,256] bf16 (64 lanes/node)
    aggregate_bf16<64><<<(N + 3) / 4, 256, 0, stream>>>(Yl, Yr, b1, rowptr, adj, h1, N);

    // layer 2: [zl|zr] = h1 @ Wc2^T   ([N,128] each, reuse xb)
    ushort* zl = xb;
    ushort* zr = xb + (size_t)N * 128;
    gemm_bf16<<<dim3(2, gm), 256, 0, stream>>>(h1, Wc2, zl, zr, N, 256, 256, 128);
    // h2  [N,128] bf16 (reuse Yl; 32 lanes/node)
    ushort* h2 = Yl;
    aggregate_bf16<32><<<(N + 7) / 8, 256, 0, stream>>>(zl, zr, b2, rowptr, adj, h2, N);

    // params p = h2 @ Wp^T + bp -> P [N,32] fp32 (8 lanes/node)
    params_kernel<<<(N + 31) / 32, 256, 0, stream>>>(h2, Wp, bp, Pp, N);
    // Cayley -> out [N,8,8] fp32
    cayley_kernel<<<(N + 255) / 256, 256, 0, stream>>>(Pp, out, N);
}

// Round 6
// 295.365 us; speedup vs baseline: 2.9884x; 1.0208x over previous
//
#include <hip/hip_runtime.h>
#include <hip/hip_bf16.h>

// ---------------------------------------------------------------------------
// InductiveBundleMapLearner: 2x SAGEConv (mean) -> linear -> Cayley map
// bf16 MFMA pipeline; fused fp32->bf16 cast in GEMM1; 128x256 tiles;
// 16B-per-lane gather aggregation with 4-deep MLP.
// ---------------------------------------------------------------------------

#define WS_ALIGN(x) (((x) + 255) & ~size_t(255))

typedef __attribute__((ext_vector_type(8))) short short8;
typedef __attribute__((ext_vector_type(4))) float floatx4;

static __device__ __forceinline__ ushort f2b(float f) {
    unsigned u = __builtin_bit_cast(unsigned, f);
    u = (u + 0x7fffu + ((u >> 16) & 1u)) >> 16;   // RNE, finite inputs
    return (ushort)u;
}
static __device__ __forceinline__ float b2f(ushort h) {
    unsigned u = ((unsigned)h) << 16;
    return __builtin_bit_cast(float, u);
}
static __device__ __forceinline__ unsigned pk2(float a, float b) {
    return (unsigned)f2b(a) | ((unsigned)f2b(b) << 16);
}

// ---------------- CSR build ----------------

__global__ void hist_kernel(const int* __restrict__ dst, int* __restrict__ deg, int E) {
    int e = blockIdx.x * blockDim.x + threadIdx.x;
    if (e < E) atomicAdd(&deg[dst[e]], 1);
}

__global__ __launch_bounds__(256)
void scan_phase1(const int* __restrict__ deg, int* __restrict__ bsum, int n) {
    __shared__ int red[256];
    const int t = threadIdx.x;
    const int i = blockIdx.x * 1024 + t * 4;
    int s = 0;
    if (i + 4 <= n) {
        int4 v = *reinterpret_cast<const int4*>(&deg[i]);
        s = v.x + v.y + v.z + v.w;
    } else {
        for (int k = i; k < n; ++k) s += deg[k];
    }
    red[t] = s;
    __syncthreads();
#pragma unroll
    for (int off = 128; off > 0; off >>= 1) {
        if (t < off) red[t] += red[t + off];
        __syncthreads();
    }
    if (t == 0) bsum[blockIdx.x] = red[0];
}

__global__ __launch_bounds__(256)
void scan_phase2(int* __restrict__ bsum, int* __restrict__ rowptr, int nb, int n) {
    __shared__ int sh[256];
    const int t = threadIdx.x;
    int orig = (t < nb) ? bsum[t] : 0;
    sh[t] = orig;
    __syncthreads();
#pragma unroll
    for (int off = 1; off < 256; off <<= 1) {
        int v = (t >= off) ? sh[t - off] : 0;
        __syncthreads();
        sh[t] += v;
        __syncthreads();
    }
    if (t < nb) bsum[t] = sh[t] - orig;          // exclusive block offsets
    if (t == 255) rowptr[n] = sh[255];           // total
}

__global__ __launch_bounds__(256)
void scan_phase3(const int* __restrict__ deg, const int* __restrict__ bsum,
                 int* __restrict__ rowptr, int n) {
    __shared__ int red[256];
    const int t = threadIdx.x;
    const int i = blockIdx.x * 1024 + t * 4;
    int v0 = 0, v1 = 0, v2 = 0, v3 = 0;
    if (i + 4 <= n) {
        int4 v = *reinterpret_cast<const int4*>(&deg[i]);
        v0 = v.x; v1 = v.y; v2 = v.z; v3 = v.w;
    } else {
        if (i     < n) v0 = deg[i];
        if (i + 1 < n) v1 = deg[i + 1];
        if (i + 2 < n) v2 = deg[i + 2];
        if (i + 3 < n) v3 = deg[i + 3];
    }
    int s = v0 + v1 + v2 + v3;
    red[t] = s;
    __syncthreads();
#pragma unroll
    for (int off = 1; off < 256; off <<= 1) {
        int u = (t >= off) ? red[t - off] : 0;
        __syncthreads();
        red[t] += u;
        __syncthreads();
    }
    int pre = bsum[blockIdx.x] + red[t] - s;
    if (i + 4 <= n) {
        int4 o;
        o.x = pre; o.y = pre + v0; o.z = pre + v0 + v1; o.w = pre + v0 + v1 + v2;
        *reinterpret_cast<int4*>(&rowptr[i]) = o;
    } else {
        if (i     < n) rowptr[i]     = pre;
        if (i + 1 < n) rowptr[i + 1] = pre + v0;
        if (i + 2 < n) rowptr[i + 2] = pre + v0 + v1;
        if (i + 3 < n) rowptr[i + 3] = pre + v0 + v1 + v2;
    }
}

__global__ void scatter_kernel(const int* __restrict__ src, const int* __restrict__ dst,
                               const int* __restrict__ rowptr, int* __restrict__ cursor,
                               int* __restrict__ adj, int E) {
    int e = blockIdx.x * blockDim.x + threadIdx.x;
    if (e < E) {
        int d = dst[e];
        int p = atomicAdd(&cursor[d], 1);
        adj[rowptr[d] + p] = src[e];
    }
}

// Wc1 = [W1l;W1r] (512x512), Wc2 = [W2l;W2r] (256x256), bf16
__global__ void build_wcat(const float* __restrict__ W1l, const float* __restrict__ W1r,
                           const float* __restrict__ W2l, const float* __restrict__ W2r,
                           ushort* __restrict__ Wc1, ushort* __restrict__ Wc2) {
    int idx = blockIdx.x * blockDim.x + threadIdx.x;
    const int n1 = (512 * 512) / 8;
    const int n2 = (256 * 256) / 8;
    const float* src;
    ushort* dst;
    if (idx < n1) {
        int e = idx * 8;
        int row = e >> 9, col = e & 511;
        src = (row < 256) ? &W1l[row * 512 + col] : &W1r[(row - 256) * 512 + col];
        dst = &Wc1[e];
    } else if (idx < n1 + n2) {
        int e = (idx - n1) * 8;
        int row = e >> 8, col = e & 255;
        src = (row < 128) ? &W2l[row * 256 + col] : &W2r[(row - 128) * 256 + col];
        dst = &Wc2[e];
    } else {
        return;
    }
    const float4* s4 = reinterpret_cast<const float4*>(src);
    float4 v0 = s4[0], v1 = s4[1];
    short8 o;
    o[0] = (short)f2b(v0.x); o[1] = (short)f2b(v0.y);
    o[2] = (short)f2b(v0.z); o[3] = (short)f2b(v0.w);
    o[4] = (short)f2b(v1.x); o[5] = (short)f2b(v1.y);
    o[6] = (short)f2b(v1.z); o[7] = (short)f2b(v1.w);
    *reinterpret_cast<short8*>(dst) = o;
}

// ---------------- bf16 MFMA GEMM: [Cl|Cr] = A @ B^T ----------------
// 128x256 tile, BK=64, 4 waves (each 64x128), 16x16x32 MFMA.
// B staged via global_load_lds (pre-swizzled src, linear dest).
// A: CASTA ? fp32 load -> bf16 pack -> swizzled ds_write (same XOR as reads)
//          : global_load_lds like B.
// LDS granule (r, g) lives at byte r*128 + ((g*16) ^ ((r&7)<<4)).

template <bool CASTA>
__global__ __launch_bounds__(256, 2)
void gemm_wide(const float* __restrict__ Af, const ushort* __restrict__ Ab,
               const ushort* __restrict__ B,
               ushort* __restrict__ Cl, ushort* __restrict__ Cr,
               int M, int K, int Ncols, int S) {
    __shared__ ushort As[128 * 64];   // 16 KB
    __shared__ ushort Bs[256 * 64];   // 32 KB
    const int tid  = threadIdx.x;
    const int wave = tid >> 6;
    const int lane = tid & 63;
    const int row0 = blockIdx.y * 128;
    const int col0 = blockIdx.x * 256;
    const int wm = (wave & 1) * 64;
    const int wn = (wave >> 1) * 128;

    floatx4 acc[4][8];
#pragma unroll
    for (int i = 0; i < 4; ++i)
#pragma unroll
        for (int j = 0; j < 8; ++j)
            acc[i][j] = (floatx4){0.f, 0.f, 0.f, 0.f};

    const int rsub = lane >> 3;                        // row within 8-row chunk
    const int ksw  = ((lane & 7) * 16) ^ (rsub << 4);  // pre-swizzled byte-in-row

    for (int k0 = 0; k0 < K; k0 += 64) {
        // ---- stage A ----
        if constexpr (CASTA) {
            // thread t: row r=t>>1, k-half h=t&1 (32 fp32), 4 granules of 8 bf16
            const int r = tid >> 1, h = tid & 1;
            int grow = row0 + r; if (grow >= M) grow = M - 1;
            const float* srow = Af + (size_t)grow * K + k0 + h * 32;
            char* lrow = (char*)As + r * 128;
            const int rx = (r & 7) << 4;
#pragma unroll
            for (int half = 0; half < 2; ++half) {
                float4 v0 = *reinterpret_cast<const float4*>(srow + half * 16 + 0);
                float4 v1 = *reinterpret_cast<const float4*>(srow + half * 16 + 4);
                float4 v2 = *reinterpret_cast<const float4*>(srow + half * 16 + 8);
                float4 v3 = *reinterpret_cast<const float4*>(srow + half * 16 + 12);
                int g0 = h * 4 + half * 2;
                uint4 o0 = make_uint4(pk2(v0.x, v0.y), pk2(v0.z, v0.w),
                                      pk2(v1.x, v1.y), pk2(v1.z, v1.w));
                uint4 o1 = make_uint4(pk2(v2.x, v2.y), pk2(v2.z, v2.w),
                                      pk2(v3.x, v3.y), pk2(v3.z, v3.w));
                *reinterpret_cast<uint4*>(lrow + ((g0 * 16) ^ rx))       = o0;
                *reinterpret_cast<uint4*>(lrow + (((g0 + 1) * 16) ^ rx)) = o1;
            }
        } else {
#pragma unroll
            for (int i = 0; i < 4; ++i) {
                int chunk = wave * 4 + i;
                int r = chunk * 8 + rsub;
                int grow = row0 + r;
                if (grow >= M) grow = M - 1;           // clamp (stores guarded)
                const char* src = (const char*)(Ab + (size_t)grow * K + k0) + ksw;
                __builtin_amdgcn_global_load_lds(
                    (const __attribute__((address_space(1))) unsigned int*)src,
                    (__attribute__((address_space(3))) unsigned int*)(&As[chunk * 512]),
                    16, 0, 0);
            }
        }
        // ---- stage B: 32 chunks of 8 rows, 8 per wave ----
#pragma unroll
        for (int i = 0; i < 8; ++i) {
            int chunk = wave * 8 + i;
            int r = chunk * 8 + rsub;
            int gcol = col0 + r;                       // Ncols % 256 == 0
            const char* src = (const char*)(B + (size_t)gcol * K + k0) + ksw;
            __builtin_amdgcn_global_load_lds(
                (const __attribute__((address_space(1))) unsigned int*)src,
                (__attribute__((address_space(3))) unsigned int*)(&Bs[chunk * 512]),
                16, 0, 0);
        }
        __syncthreads();

#pragma unroll
        for (int kk = 0; kk < 2; ++kk) {
            short8 af[4], bf[8];
            const int kb = (kk * 64 + ((lane >> 4) << 4)) ^ ((lane & 7) << 4);
#pragma unroll
            for (int im = 0; im < 4; ++im) {
                int r = wm + im * 16 + (lane & 15);
                af[im] = *reinterpret_cast<const short8*>((const char*)As + r * 128 + kb);
            }
#pragma unroll
            for (int in = 0; in < 8; ++in) {
                int r = wn + in * 16 + (lane & 15);
                bf[in] = *reinterpret_cast<const short8*>((const char*)Bs + r * 128 + kb);
            }
#pragma unroll
            for (int im = 0; im < 4; ++im)
#pragma unroll
                for (int in = 0; in < 8; ++in)
                    acc[im][in] = __builtin_amdgcn_mfma_f32_16x16x32_bf16(
                        af[im], bf[in], acc[im][in], 0, 0, 0);
        }
        __syncthreads();
    }

    // epilogue: C/D layout col=lane&15, row=(lane>>4)*4+reg
#pragma unroll
    for (int im = 0; im < 4; ++im) {
#pragma unroll
        for (int reg = 0; reg < 4; ++reg) {
            int r = row0 + wm + im * 16 + ((lane >> 4) << 2) + reg;
            if (r < M) {
#pragma unroll
                for (int in = 0; in < 8; ++in) {
                    int g = col0 + wn + in * 16 + (lane & 15);
                    if (g < S) Cl[(size_t)r * S + g] = f2b(acc[im][in][reg]);
                    else       Cr[(size_t)r * S + (g - S)] = f2b(acc[im][in][reg]);
                }
            }
        }
    }
}

// ---------------- aggregation: h = relu(mean_l + self_r + b), bf16 ----------------
// Yl/Yr = [N, F] split buffers. LPN lanes/node, 8 ch/lane (16B short8 loads).
// Edge loop unrolled x4: 4 x 16B in flight per lane.

template <int LPN>
__global__ __launch_bounds__(256)
void aggregate_bf16(const ushort* __restrict__ Yl, const ushort* __restrict__ Yr,
                    const float* __restrict__ bias,
                    const int* __restrict__ rowptr, const int* __restrict__ adj,
                    ushort* __restrict__ H, int n) {
    constexpr int F = LPN * 8;
    const int grp = threadIdx.x / LPN;
    const int sub = threadIdx.x % LPN;
    const int node = blockIdx.x * (256 / LPN) + grp;
    if (node >= n) return;
    const int c = sub * 8;
    const int start = rowptr[node], end = rowptr[node + 1];

    float acc[8];
#pragma unroll
    for (int v = 0; v < 8; ++v) acc[v] = 0.f;

    int e = start;
    for (; e + 4 <= end; e += 4) {
        int s0 = adj[e + 0], s1 = adj[e + 1], s2 = adj[e + 2], s3 = adj[e + 3];
        short8 r0 = *reinterpret_cast<const short8*>(&Yl[(size_t)s0 * F + c]);
        short8 r1 = *reinterpret_cast<const short8*>(&Yl[(size_t)s1 * F + c]);
        short8 r2 = *reinterpret_cast<const short8*>(&Yl[(size_t)s2 * F + c]);
        short8 r3 = *reinterpret_cast<const short8*>(&Yl[(size_t)s3 * F + c]);
#pragma unroll
        for (int v = 0; v < 8; ++v)
            acc[v] += (b2f((ushort)r0[v]) + b2f((ushort)r1[v])) +
                      (b2f((ushort)r2[v]) + b2f((ushort)r3[v]));
    }
    for (; e < end; ++e) {
        int s = adj[e];
        short8 r = *reinterpret_cast<const short8*>(&Yl[(size_t)s * F + c]);
#pragma unroll
        for (int v = 0; v < 8; ++v) acc[v] += b2f((ushort)r[v]);
    }

    const int d = end - start;
    const float inv = 1.0f / (float)(d > 0 ? d : 1);
    short8 sv = *reinterpret_cast<const short8*>(&Yr[(size_t)node * F + c]);
    float4 bv0 = *reinterpret_cast<const float4*>(&bias[c]);
    float4 bv1 = *reinterpret_cast<const float4*>(&bias[c + 4]);
    float bb[8] = {bv0.x, bv0.y, bv0.z, bv0.w, bv1.x, bv1.y, bv1.z, bv1.w};
    short8 o;
#pragma unroll
    for (int v = 0; v < 8; ++v)
        o[v] = (short)f2b(fmaxf(acc[v] * inv + b2f((ushort)sv[v]) + bb[v], 0.f));
    *reinterpret_cast<short8*>(&H[(size_t)node * F + c]) = o;
}

// ---------------- params: p = h2 @ Wp^T + bp -> P[N,32] ----------------
// 8 lanes/node; lane l owns params {l, l+8, l+16, l+24}; pitch-132 LDS.

__global__ __launch_bounds__(256)
void params_kernel(const ushort* __restrict__ H2, const float* __restrict__ Wp,
                   const float* __restrict__ bp, float* __restrict__ P, int n) {
    __shared__ float WpS[32 * 132];
    __shared__ float bpS[32];
    for (int t = threadIdx.x; t < 32 * 132; t += 256) WpS[t] = 0.f;
    if (threadIdx.x < 32) bpS[threadIdx.x] = (threadIdx.x < 28) ? bp[threadIdx.x] : 0.f;
    __syncthreads();
    for (int t = threadIdx.x; t < 28 * 128; t += 256) {
        int r = t >> 7, c = t & 127;
        WpS[r * 132 + c] = Wp[t];
    }
    __syncthreads();

    const int node = blockIdx.x * 32 + (threadIdx.x >> 3);
    const int l = threadIdx.x & 7;
    if (node >= n) return;

    short8 h8[16];
    const short8* hp = reinterpret_cast<const short8*>(&H2[(size_t)node * 128]);
#pragma unroll
    for (int q = 0; q < 16; ++q) h8[q] = hp[q];

    float acc0 = bpS[l], acc1 = bpS[l + 8], acc2 = bpS[l + 16], acc3 = bpS[l + 24];
#pragma unroll
    for (int q = 0; q < 32; ++q) {
        float h0 = b2f((ushort)h8[q >> 1][(q & 1) * 4 + 0]);
        float h1 = b2f((ushort)h8[q >> 1][(q & 1) * 4 + 1]);
        float h2 = b2f((ushort)h8[q >> 1][(q & 1) * 4 + 2]);
        float h3 = b2f((ushort)h8[q >> 1][(q & 1) * 4 + 3]);
        float4 w0 = *reinterpret_cast<const float4*>(&WpS[(l +  0) * 132 + 4 * q]);
        float4 w1 = *reinterpret_cast<const float4*>(&WpS[(l +  8) * 132 + 4 * q]);
        float4 w2 = *reinterpret_cast<const float4*>(&WpS[(l + 16) * 132 + 4 * q]);
        float4 w3 = *reinterpret_cast<const float4*>(&WpS[(l + 24) * 132 + 4 * q]);
        acc0 += h0 * w0.x + h1 * w0.y + h2 * w0.z + h3 * w0.w;
        acc1 += h0 * w1.x + h1 * w1.y + h2 * w1.z + h3 * w1.w;
        acc2 += h0 * w2.x + h1 * w2.y + h2 * w2.z + h3 * w2.w;
        acc3 += h0 * w3.x + h1 * w3.y + h2 * w3.z + h3 * w3.w;
    }
    float* pout = &P[(size_t)node * 32];
    pout[l]      = acc0;
    pout[l + 8]  = acc1;
    pout[l + 16] = acc2;
    pout[l + 24] = acc3;
}

// ---------------- Cayley: O = (I-A)^{-1}(I+A) ----------------

__global__ __launch_bounds__(256)
void cayley_kernel(const float* __restrict__ P, float* __restrict__ Out, int n) {
    int i = blockIdx.x * blockDim.x + threadIdx.x;
    if (i >= n) return;
    float p[28];
    const float4* pp = reinterpret_cast<const float4*>(&P[(size_t)i * 32]);
#pragma unroll
    for (int q = 0; q < 7; ++q) {
        float4 v = pp[q];
        p[4 * q + 0] = v.x; p[4 * q + 1] = v.y;
        p[4 * q + 2] = v.z; p[4 * q + 3] = v.w;
    }

    float M_[8][8], B_[8][8];
#pragma unroll
    for (int r = 0; r < 8; ++r)
#pragma unroll
        for (int c = 0; c < 8; ++c) {
            M_[r][c] = (r == c) ? 1.f : 0.f;
            B_[r][c] = (r == c) ? 1.f : 0.f;
        }
    {
        int idx = 0;
#pragma unroll
        for (int r = 0; r < 8; ++r)
#pragma unroll
            for (int c = r + 1; c < 8; ++c) {
                float a = p[idx++];
                M_[r][c] -= a;  M_[c][r] += a;
                B_[r][c] += a;  B_[c][r] -= a;
            }
    }
#pragma unroll
    for (int col = 0; col < 8; ++col) {
        float inv = 1.0f / M_[col][col];
#pragma unroll
        for (int c = 0; c < 8; ++c) { M_[col][c] *= inv; B_[col][c] *= inv; }
#pragma unroll
        for (int r = 0; r < 8; ++r) {
            if (r == col) continue;
            float f = M_[r][col];
#pragma unroll
            for (int c = 0; c < 8; ++c) {
                M_[r][c] -= f * M_[col][c];
                B_[r][c] -= f * B_[col][c];
            }
        }
    }
    float* out = &Out[(size_t)i * 64];
#pragma unroll
    for (int r = 0; r < 8; ++r) {
        float4 o0 = make_float4(B_[r][0], B_[r][1], B_[r][2], B_[r][3]);
        float4 o1 = make_float4(B_[r][4], B_[r][5], B_[r][6], B_[r][7]);
        *reinterpret_cast<float4*>(&out[r * 8 + 0]) = o0;
        *reinterpret_cast<float4*>(&out[r * 8 + 4]) = o1;
    }
}

// ---------------------------------------------------------------------------

extern "C" void kernel_launch(void* const* d_in, const int* in_sizes, int n_in,
                              void* d_out, int out_size, void* d_ws, size_t ws_size,
                              hipStream_t stream) {
    const float* x   = (const float*)d_in[0];
    const int*   ei  = (const int*)d_in[1];
    const float* W1l = (const float*)d_in[2];
    const float* b1  = (const float*)d_in[3];
    const float* W1r = (const float*)d_in[4];
    const float* W2l = (const float*)d_in[5];
    const float* b2  = (const float*)d_in[6];
    const float* W2r = (const float*)d_in[7];
    const float* Wp  = (const float*)d_in[8];
    const float* bp  = (const float*)d_in[9];
    float* out = (float*)d_out;

    const int IN_DIM = 512;
    const int N = in_sizes[0] / IN_DIM;   // 50000
    const int E = in_sizes[1] / 2;        // 800000

    char* ws = (char*)d_ws;
    size_t off = 0;
    int* deg      = (int*)(ws + off); off = WS_ALIGN(off + (size_t)N * 4);
    int* rowptr   = (int*)(ws + off); off = WS_ALIGN(off + (size_t)(N + 1) * 4);
    int* cursor   = (int*)(ws + off); off = WS_ALIGN(off + (size_t)N * 4);
    int* bsum     = (int*)(ws + off); off = WS_ALIGN(off + (size_t)256 * 4);
    int* adj      = (int*)(ws + off); off = WS_ALIGN(off + (size_t)E * 4);
    ushort* Yl    = (ushort*)(ws + off); off = WS_ALIGN(off + (size_t)N * 256 * 2);
    ushort* Yr    = (ushort*)(ws + off); off = WS_ALIGN(off + (size_t)N * 256 * 2);
    ushort* h1    = (ushort*)(ws + off); off = WS_ALIGN(off + (size_t)N * 256 * 2);
    ushort* zl    = (ushort*)(ws + off); off = WS_ALIGN(off + (size_t)N * 128 * 2);
    ushort* zr    = (ushort*)(ws + off); off = WS_ALIGN(off + (size_t)N * 128 * 2);
    ushort* Wc1   = (ushort*)(ws + off); off = WS_ALIGN(off + (size_t)512 * 512 * 2);
    ushort* Wc2   = (ushort*)(ws + off); off = WS_ALIGN(off + (size_t)256 * 256 * 2);
    float*  Pp    = (float*)(ws + off);  off = WS_ALIGN(off + (size_t)N * 32 * 4);

    const int* src = ei;
    const int* dst = ei + E;

    hipMemsetAsync(deg, 0, (size_t)N * 4, stream);
    hipMemsetAsync(cursor, 0, (size_t)N * 4, stream);

    int eb = (E + 255) / 256;
    int nb = (N + 1023) / 1024;   // <= 256
    hist_kernel<<<eb, 256, 0, stream>>>(dst, deg, E);
    scan_phase1<<<nb, 256, 0, stream>>>(deg, bsum, N);
    scan_phase2<<<1, 256, 0, stream>>>(bsum, rowptr, nb, N);
    scan_phase3<<<nb, 256, 0, stream>>>(deg, bsum, rowptr, N);
    scatter_kernel<<<eb, 256, 0, stream>>>(src, dst, rowptr, cursor, adj, E);

    build_wcat<<<((512 * 512 + 256 * 256) / 8 + 255) / 256, 256, 0, stream>>>(
        W1l, W1r, W2l, W2r, Wc1, Wc2);

    int gm = (N + 127) / 128;   // 391

    // layer 1: [Yl|Yr] = bf16(x) @ Wc1^T  (fused cast, [N,256] each)
    gemm_wide<true><<<dim3(2, gm), 256, 0, stream>>>(
        x, (const ushort*)nullptr, Wc1, Yl, Yr, N, 512, 512, 256);
    // h1 = relu(mean + self + b1)  [N,256] bf16 (32 lanes/node, 16B loads)
    aggregate_bf16<32><<<(N + 7) / 8, 256, 0, stream>>>(Yl, Yr, b1, rowptr, adj, h1, N);

    // layer 2: [zl|zr] = h1 @ Wc2^T   ([N,128] each)
    gemm_wide<false><<<dim3(1, gm), 256, 0, stream>>>(
        (const float*)nullptr, h1, Wc2, zl, zr, N, 256, 256, 128);
    // h2  [N,128] bf16 (reuse Yl; 16 lanes/node)
    ushort* h2 = Yl;
    aggregate_bf16<16><<<(N + 15) / 16, 256, 0, stream>>>(zl, zr, b2, rowptr, adj, h2, N);

    // params p = h2 @ Wp^T + bp -> P [N,32] fp32 (8 lanes/node)
    params_kernel<<<(N + 31) / 32, 256, 0, stream>>>(h2, Wp, bp, Pp, N);
    // Cayley -> out [N,8,8] fp32
    cayley_kernel<<<(N + 255) / 256, 256, 0, stream>>>(Pp, out, N);
}

// Round 7
// 276.678 us; speedup vs baseline: 3.1902x; 1.0675x over previous
//
#include <hip/hip_runtime.h>
#include <hip/hip_bf16.h>

// ---------------------------------------------------------------------------
// InductiveBundleMapLearner: 2x SAGEConv (mean) -> linear -> Cayley map
// bf16 MFMA pipeline; fused+pipelined fp32->bf16 cast in GEMM1; 128x256 tile
// with 8 waves (64x64 each); 16B-per-lane gather aggregation.
// ---------------------------------------------------------------------------

#define WS_ALIGN(x) (((x) + 255) & ~size_t(255))

typedef __attribute__((ext_vector_type(8))) short short8;
typedef __attribute__((ext_vector_type(4))) float floatx4;

static __device__ __forceinline__ ushort f2b(float f) {
    unsigned u = __builtin_bit_cast(unsigned, f);
    u = (u + 0x7fffu + ((u >> 16) & 1u)) >> 16;   // RNE, finite inputs
    return (ushort)u;
}
static __device__ __forceinline__ float b2f(ushort h) {
    unsigned u = ((unsigned)h) << 16;
    return __builtin_bit_cast(float, u);
}
static __device__ __forceinline__ unsigned pk2(float a, float b) {
    return (unsigned)f2b(a) | ((unsigned)f2b(b) << 16);
}

// ---------------- CSR build ----------------

__global__ void hist_kernel(const int* __restrict__ dst, int* __restrict__ deg, int E) {
    int e = blockIdx.x * blockDim.x + threadIdx.x;
    if (e < E) atomicAdd(&deg[dst[e]], 1);
}

__global__ __launch_bounds__(256)
void scan_phase1(const int* __restrict__ deg, int* __restrict__ bsum, int n) {
    __shared__ int red[256];
    const int t = threadIdx.x;
    const int i = blockIdx.x * 1024 + t * 4;
    int s = 0;
    if (i + 4 <= n) {
        int4 v = *reinterpret_cast<const int4*>(&deg[i]);
        s = v.x + v.y + v.z + v.w;
    } else {
        for (int k = i; k < n; ++k) s += deg[k];
    }
    red[t] = s;
    __syncthreads();
#pragma unroll
    for (int off = 128; off > 0; off >>= 1) {
        if (t < off) red[t] += red[t + off];
        __syncthreads();
    }
    if (t == 0) bsum[blockIdx.x] = red[0];
}

__global__ __launch_bounds__(256)
void scan_phase2(int* __restrict__ bsum, int* __restrict__ rowptr, int nb, int n) {
    __shared__ int sh[256];
    const int t = threadIdx.x;
    int orig = (t < nb) ? bsum[t] : 0;
    sh[t] = orig;
    __syncthreads();
#pragma unroll
    for (int off = 1; off < 256; off <<= 1) {
        int v = (t >= off) ? sh[t - off] : 0;
        __syncthreads();
        sh[t] += v;
        __syncthreads();
    }
    if (t < nb) bsum[t] = sh[t] - orig;          // exclusive block offsets
    if (t == 255) rowptr[n] = sh[255];           // total
}

__global__ __launch_bounds__(256)
void scan_phase3(const int* __restrict__ deg, const int* __restrict__ bsum,
                 int* __restrict__ rowptr, int n) {
    __shared__ int red[256];
    const int t = threadIdx.x;
    const int i = blockIdx.x * 1024 + t * 4;
    int v0 = 0, v1 = 0, v2 = 0, v3 = 0;
    if (i + 4 <= n) {
        int4 v = *reinterpret_cast<const int4*>(&deg[i]);
        v0 = v.x; v1 = v.y; v2 = v.z; v3 = v.w;
    } else {
        if (i     < n) v0 = deg[i];
        if (i + 1 < n) v1 = deg[i + 1];
        if (i + 2 < n) v2 = deg[i + 2];
        if (i + 3 < n) v3 = deg[i + 3];
    }
    int s = v0 + v1 + v2 + v3;
    red[t] = s;
    __syncthreads();
#pragma unroll
    for (int off = 1; off < 256; off <<= 1) {
        int u = (t >= off) ? red[t - off] : 0;
        __syncthreads();
        red[t] += u;
        __syncthreads();
    }
    int pre = bsum[blockIdx.x] + red[t] - s;
    if (i + 4 <= n) {
        int4 o;
        o.x = pre; o.y = pre + v0; o.z = pre + v0 + v1; o.w = pre + v0 + v1 + v2;
        *reinterpret_cast<int4*>(&rowptr[i]) = o;
    } else {
        if (i     < n) rowptr[i]     = pre;
        if (i + 1 < n) rowptr[i + 1] = pre + v0;
        if (i + 2 < n) rowptr[i + 2] = pre + v0 + v1;
        if (i + 3 < n) rowptr[i + 3] = pre + v0 + v1 + v2;
    }
}

__global__ void scatter_kernel(const int* __restrict__ src, const int* __restrict__ dst,
                               const int* __restrict__ rowptr, int* __restrict__ cursor,
                               int* __restrict__ adj, int E) {
    int e = blockIdx.x * blockDim.x + threadIdx.x;
    if (e < E) {
        int d = dst[e];
        int p = atomicAdd(&cursor[d], 1);
        adj[rowptr[d] + p] = src[e];
    }
}

// Wc1 = [W1l;W1r] (512x512), Wc2 = [W2l;W2r] (256x256), bf16
__global__ void build_wcat(const float* __restrict__ W1l, const float* __restrict__ W1r,
                           const float* __restrict__ W2l, const float* __restrict__ W2r,
                           ushort* __restrict__ Wc1, ushort* __restrict__ Wc2) {
    int idx = blockIdx.x * blockDim.x + threadIdx.x;
    const int n1 = (512 * 512) / 8;
    const int n2 = (256 * 256) / 8;
    const float* src;
    ushort* dst;
    if (idx < n1) {
        int e = idx * 8;
        int row = e >> 9, col = e & 511;
        src = (row < 256) ? &W1l[row * 512 + col] : &W1r[(row - 256) * 512 + col];
        dst = &Wc1[e];
    } else if (idx < n1 + n2) {
        int e = (idx - n1) * 8;
        int row = e >> 8, col = e & 255;
        src = (row < 128) ? &W2l[row * 256 + col] : &W2r[(row - 128) * 256 + col];
        dst = &Wc2[e];
    } else {
        return;
    }
    const float4* s4 = reinterpret_cast<const float4*>(src);
    float4 v0 = s4[0], v1 = s4[1];
    short8 o;
    o[0] = (short)f2b(v0.x); o[1] = (short)f2b(v0.y);
    o[2] = (short)f2b(v0.z); o[3] = (short)f2b(v0.w);
    o[4] = (short)f2b(v1.x); o[5] = (short)f2b(v1.y);
    o[6] = (short)f2b(v1.z); o[7] = (short)f2b(v1.w);
    *reinterpret_cast<short8*>(dst) = o;
}

// ---------------- bf16 MFMA GEMM: [Cl|Cr] = A @ B^T ----------------
// 128x256 tile, BK=64, 512 threads = 8 waves (each 64x64), 16x16x32 MFMA.
// B staged via global_load_lds (pre-swizzled src, linear dest).
// A: CASTA ? pipelined fp32 reg-load -> bf16 pack -> swizzled ds_write
//          : global_load_lds like B.
// LDS granule (r, g) lives at byte r*128 + ((g*16) ^ ((r&7)<<4)).

template <bool CASTA>
__global__ __launch_bounds__(512, 4)
void gemm_wide(const float* __restrict__ Af, const ushort* __restrict__ Ab,
               const ushort* __restrict__ B,
               ushort* __restrict__ Cl, ushort* __restrict__ Cr,
               int M, int K, int Ncols, int S) {
    __shared__ ushort As[128 * 64];   // 16 KB
    __shared__ ushort Bs[256 * 64];   // 32 KB
    const int tid  = threadIdx.x;
    const int wave = tid >> 6;
    const int lane = tid & 63;
    const int row0 = blockIdx.y * 128;
    const int col0 = blockIdx.x * 256;
    const int wm = (wave & 1) * 64;
    const int wn = (wave >> 1) * 64;

    floatx4 acc[4][4];
#pragma unroll
    for (int i = 0; i < 4; ++i)
#pragma unroll
        for (int j = 0; j < 4; ++j)
            acc[i][j] = (floatx4){0.f, 0.f, 0.f, 0.f};

    const int rsub = lane >> 3;                        // row within 8-row chunk
    const int ksw  = ((lane & 7) * 16) ^ (rsub << 4);  // pre-swizzled byte-in-row

    // CASTA addressing: thread owns row r = tid>>2, quarter qt = tid&3
    const int ar = tid >> 2;
    const int aq = tid & 3;
    int agrow = row0 + ar; if (agrow >= M) agrow = M - 1;
    const float* arow_base = CASTA ? (Af + (size_t)agrow * K + aq * 16) : nullptr;
    char* alds = (char*)As + ar * 128;
    const int arx = (ar & 7) << 4;

    float4 va0, va1, va2, va3;
    if constexpr (CASTA) {
        const float* s0 = arow_base;                   // k0 = 0 prologue
        va0 = *reinterpret_cast<const float4*>(s0 + 0);
        va1 = *reinterpret_cast<const float4*>(s0 + 4);
        va2 = *reinterpret_cast<const float4*>(s0 + 8);
        va3 = *reinterpret_cast<const float4*>(s0 + 12);
    }

    for (int k0 = 0; k0 < K; k0 += 64) {
        // ---- issue B DMA first (longest queue) : 32 chunks, 4 per wave ----
#pragma unroll
        for (int i = 0; i < 4; ++i) {
            int chunk = wave * 4 + i;
            int r = chunk * 8 + rsub;
            int gcol = col0 + r;                       // Ncols % 256 == 0
            const char* src = (const char*)(B + (size_t)gcol * K + k0) + ksw;
            __builtin_amdgcn_global_load_lds(
                (const __attribute__((address_space(1))) unsigned int*)src,
                (__attribute__((address_space(3))) unsigned int*)(&Bs[chunk * 512]),
                16, 0, 0);
        }
        // ---- stage A ----
        if constexpr (CASTA) {
            // pack current regs -> LDS (2 granules of 8 bf16)
            uint4 o0 = make_uint4(pk2(va0.x, va0.y), pk2(va0.z, va0.w),
                                  pk2(va1.x, va1.y), pk2(va1.z, va1.w));
            uint4 o1 = make_uint4(pk2(va2.x, va2.y), pk2(va2.z, va2.w),
                                  pk2(va3.x, va3.y), pk2(va3.z, va3.w));
            int g0 = aq * 2;
            *reinterpret_cast<uint4*>(alds + ((g0 * 16) ^ arx))       = o0;
            *reinterpret_cast<uint4*>(alds + (((g0 + 1) * 16) ^ arx)) = o1;
            // prefetch next k-tile (drained by the barrier below)
            if (k0 + 64 < K) {
                const float* s1 = arow_base + k0 + 64;
                va0 = *reinterpret_cast<const float4*>(s1 + 0);
                va1 = *reinterpret_cast<const float4*>(s1 + 4);
                va2 = *reinterpret_cast<const float4*>(s1 + 8);
                va3 = *reinterpret_cast<const float4*>(s1 + 12);
            }
        } else {
            // 16 chunks, 2 per wave
#pragma unroll
            for (int i = 0; i < 2; ++i) {
                int chunk = wave * 2 + i;
                int r = chunk * 8 + rsub;
                int grow = row0 + r;
                if (grow >= M) grow = M - 1;           // clamp (stores guarded)
                const char* src = (const char*)(Ab + (size_t)grow * K + k0) + ksw;
                __builtin_amdgcn_global_load_lds(
                    (const __attribute__((address_space(1))) unsigned int*)src,
                    (__attribute__((address_space(3))) unsigned int*)(&As[chunk * 512]),
                    16, 0, 0);
            }
        }
        __syncthreads();

#pragma unroll
        for (int kk = 0; kk < 2; ++kk) {
            short8 af[4], bf[4];
            const int kb = (kk * 64 + ((lane >> 4) << 4)) ^ ((lane & 7) << 4);
#pragma unroll
            for (int im = 0; im < 4; ++im) {
                int r = wm + im * 16 + (lane & 15);
                af[im] = *reinterpret_cast<const short8*>((const char*)As + r * 128 + kb);
            }
#pragma unroll
            for (int in = 0; in < 4; ++in) {
                int r = wn + in * 16 + (lane & 15);
                bf[in] = *reinterpret_cast<const short8*>((const char*)Bs + r * 128 + kb);
            }
#pragma unroll
            for (int im = 0; im < 4; ++im)
#pragma unroll
                for (int in = 0; in < 4; ++in)
                    acc[im][in] = __builtin_amdgcn_mfma_f32_16x16x32_bf16(
                        af[im], bf[in], acc[im][in], 0, 0, 0);
        }
        __syncthreads();
    }

    // epilogue: C/D layout col=lane&15, row=(lane>>4)*4+reg
#pragma unroll
    for (int im = 0; im < 4; ++im) {
#pragma unroll
        for (int reg = 0; reg < 4; ++reg) {
            int r = row0 + wm + im * 16 + ((lane >> 4) << 2) + reg;
            if (r < M) {
#pragma unroll
                for (int in = 0; in < 4; ++in) {
                    int g = col0 + wn + in * 16 + (lane & 15);
                    if (g < S) Cl[(size_t)r * S + g] = f2b(acc[im][in][reg]);
                    else       Cr[(size_t)r * S + (g - S)] = f2b(acc[im][in][reg]);
                }
            }
        }
    }
}

// ---------------- aggregation: h = relu(mean_l + self_r + b), bf16 ----------------
// Yl/Yr = [N, F] split buffers. LPN lanes/node, 8 ch/lane (16B short8 loads).
// Edge loop unrolled x4: 4 x 16B in flight per lane.

template <int LPN>
__global__ __launch_bounds__(256)
void aggregate_bf16(const ushort* __restrict__ Yl, const ushort* __restrict__ Yr,
                    const float* __restrict__ bias,
                    const int* __restrict__ rowptr, const int* __restrict__ adj,
                    ushort* __restrict__ H, int n) {
    constexpr int F = LPN * 8;
    const int grp = threadIdx.x / LPN;
    const int sub = threadIdx.x % LPN;
    const int node = blockIdx.x * (256 / LPN) + grp;
    if (node >= n) return;
    const int c = sub * 8;
    const int start = rowptr[node], end = rowptr[node + 1];

    float acc[8];
#pragma unroll
    for (int v = 0; v < 8; ++v) acc[v] = 0.f;

    int e = start;
    for (; e + 4 <= end; e += 4) {
        int s0 = adj[e + 0], s1 = adj[e + 1], s2 = adj[e + 2], s3 = adj[e + 3];
        short8 r0 = *reinterpret_cast<const short8*>(&Yl[(size_t)s0 * F + c]);
        short8 r1 = *reinterpret_cast<const short8*>(&Yl[(size_t)s1 * F + c]);
        short8 r2 = *reinterpret_cast<const short8*>(&Yl[(size_t)s2 * F + c]);
        short8 r3 = *reinterpret_cast<const short8*>(&Yl[(size_t)s3 * F + c]);
#pragma unroll
        for (int v = 0; v < 8; ++v)
            acc[v] += (b2f((ushort)r0[v]) + b2f((ushort)r1[v])) +
                      (b2f((ushort)r2[v]) + b2f((ushort)r3[v]));
    }
    for (; e < end; ++e) {
        int s = adj[e];
        short8 r = *reinterpret_cast<const short8*>(&Yl[(size_t)s * F + c]);
#pragma unroll
        for (int v = 0; v < 8; ++v) acc[v] += b2f((ushort)r[v]);
    }

    const int d = end - start;
    const float inv = 1.0f / (float)(d > 0 ? d : 1);
    short8 sv = *reinterpret_cast<const short8*>(&Yr[(size_t)node * F + c]);
    float4 bv0 = *reinterpret_cast<const float4*>(&bias[c]);
    float4 bv1 = *reinterpret_cast<const float4*>(&bias[c + 4]);
    float bb[8] = {bv0.x, bv0.y, bv0.z, bv0.w, bv1.x, bv1.y, bv1.z, bv1.w};
    short8 o;
#pragma unroll
    for (int v = 0; v < 8; ++v)
        o[v] = (short)f2b(fmaxf(acc[v] * inv + b2f((ushort)sv[v]) + bb[v], 0.f));
    *reinterpret_cast<short8*>(&H[(size_t)node * F + c]) = o;
}

// ---------------- params: p = h2 @ Wp^T + bp -> P[N,32] ----------------
// 8 lanes/node; lane l owns params {l, l+8, l+16, l+24}; pitch-132 LDS.

__global__ __launch_bounds__(256)
void params_kernel(const ushort* __restrict__ H2, const float* __restrict__ Wp,
                   const float* __restrict__ bp, float* __restrict__ P, int n) {
    __shared__ float WpS[32 * 132];
    __shared__ float bpS[32];
    for (int t = threadIdx.x; t < 32 * 132; t += 256) WpS[t] = 0.f;
    if (threadIdx.x < 32) bpS[threadIdx.x] = (threadIdx.x < 28) ? bp[threadIdx.x] : 0.f;
    __syncthreads();
    for (int t = threadIdx.x; t < 28 * 128; t += 256) {
        int r = t >> 7, c = t & 127;
        WpS[r * 132 + c] = Wp[t];
    }
    __syncthreads();

    const int node = blockIdx.x * 32 + (threadIdx.x >> 3);
    const int l = threadIdx.x & 7;
    if (node >= n) return;

    short8 h8[16];
    const short8* hp = reinterpret_cast<const short8*>(&H2[(size_t)node * 128]);
#pragma unroll
    for (int q = 0; q < 16; ++q) h8[q] = hp[q];

    float acc0 = bpS[l], acc1 = bpS[l + 8], acc2 = bpS[l + 16], acc3 = bpS[l + 24];
#pragma unroll
    for (int q = 0; q < 32; ++q) {
        float h0 = b2f((ushort)h8[q >> 1][(q & 1) * 4 + 0]);
        float h1 = b2f((ushort)h8[q >> 1][(q & 1) * 4 + 1]);
        float h2 = b2f((ushort)h8[q >> 1][(q & 1) * 4 + 2]);
        float h3 = b2f((ushort)h8[q >> 1][(q & 1) * 4 + 3]);
        float4 w0 = *reinterpret_cast<const float4*>(&WpS[(l +  0) * 132 + 4 * q]);
        float4 w1 = *reinterpret_cast<const float4*>(&WpS[(l +  8) * 132 + 4 * q]);
        float4 w2 = *reinterpret_cast<const float4*>(&WpS[(l + 16) * 132 + 4 * q]);
        float4 w3 = *reinterpret_cast<const float4*>(&WpS[(l + 24) * 132 + 4 * q]);
        acc0 += h0 * w0.x + h1 * w0.y + h2 * w0.z + h3 * w0.w;
        acc1 += h0 * w1.x + h1 * w1.y + h2 * w1.z + h3 * w1.w;
        acc2 += h0 * w2.x + h1 * w2.y + h2 * w2.z + h3 * w2.w;
        acc3 += h0 * w3.x + h1 * w3.y + h2 * w3.z + h3 * w3.w;
    }
    float* pout = &P[(size_t)node * 32];
    pout[l]      = acc0;
    pout[l + 8]  = acc1;
    pout[l + 16] = acc2;
    pout[l + 24] = acc3;
}

// ---------------- Cayley: O = (I-A)^{-1}(I+A) ----------------

__global__ __launch_bounds__(256)
void cayley_kernel(const float* __restrict__ P, float* __restrict__ Out, int n) {
    int i = blockIdx.x * blockDim.x + threadIdx.x;
    if (i >= n) return;
    float p[28];
    const float4* pp = reinterpret_cast<const float4*>(&P[(size_t)i * 32]);
#pragma unroll
    for (int q = 0; q < 7; ++q) {
        float4 v = pp[q];
        p[4 * q + 0] = v.x; p[4 * q + 1] = v.y;
        p[4 * q + 2] = v.z; p[4 * q + 3] = v.w;
    }

    float M_[8][8], B_[8][8];
#pragma unroll
    for (int r = 0; r < 8; ++r)
#pragma unroll
        for (int c = 0; c < 8; ++c) {
            M_[r][c] = (r == c) ? 1.f : 0.f;
            B_[r][c] = (r == c) ? 1.f : 0.f;
        }
    {
        int idx = 0;
#pragma unroll
        for (int r = 0; r < 8; ++r)
#pragma unroll
            for (int c = r + 1; c < 8; ++c) {
                float a = p[idx++];
                M_[r][c] -= a;  M_[c][r] += a;
                B_[r][c] += a;  B_[c][r] -= a;
            }
    }
#pragma unroll
    for (int col = 0; col < 8; ++col) {
        float inv = 1.0f / M_[col][col];
#pragma unroll
        for (int c = 0; c < 8; ++c) { M_[col][c] *= inv; B_[col][c] *= inv; }
#pragma unroll
        for (int r = 0; r < 8; ++r) {
            if (r == col) continue;
            float f = M_[r][col];
#pragma unroll
            for (int c = 0; c < 8; ++c) {
                M_[r][c] -= f * M_[col][c];
                B_[r][c] -= f * B_[col][c];
            }
        }
    }
    float* out = &Out[(size_t)i * 64];
#pragma unroll
    for (int r = 0; r < 8; ++r) {
        float4 o0 = make_float4(B_[r][0], B_[r][1], B_[r][2], B_[r][3]);
        float4 o1 = make_float4(B_[r][4], B_[r][5], B_[r][6], B_[r][7]);
        *reinterpret_cast<float4*>(&out[r * 8 + 0]) = o0;
        *reinterpret_cast<float4*>(&out[r * 8 + 4]) = o1;
    }
}

// ---------------------------------------------------------------------------

extern "C" void kernel_launch(void* const* d_in, const int* in_sizes, int n_in,
                              void* d_out, int out_size, void* d_ws, size_t ws_size,
                              hipStream_t stream) {
    const float* x   = (const float*)d_in[0];
    const int*   ei  = (const int*)d_in[1];
    const float* W1l = (const float*)d_in[2];
    const float* b1  = (const float*)d_in[3];
    const float* W1r = (const float*)d_in[4];
    const float* W2l = (const float*)d_in[5];
    const float* b2  = (const float*)d_in[6];
    const float* W2r = (const float*)d_in[7];
    const float* Wp  = (const float*)d_in[8];
    const float* bp  = (const float*)d_in[9];
    float* out = (float*)d_out;

    const int IN_DIM = 512;
    const int N = in_sizes[0] / IN_DIM;   // 50000
    const int E = in_sizes[1] / 2;        // 800000

    char* ws = (char*)d_ws;
    size_t off = 0;
    int* deg      = (int*)(ws + off); off = WS_ALIGN(off + (size_t)N * 4);
    int* rowptr   = (int*)(ws + off); off = WS_ALIGN(off + (size_t)(N + 1) * 4);
    int* cursor   = (int*)(ws + off); off = WS_ALIGN(off + (size_t)N * 4);
    int* bsum     = (int*)(ws + off); off = WS_ALIGN(off + (size_t)256 * 4);
    int* adj      = (int*)(ws + off); off = WS_ALIGN(off + (size_t)E * 4);
    ushort* Yl    = (ushort*)(ws + off); off = WS_ALIGN(off + (size_t)N * 256 * 2);
    ushort* Yr    = (ushort*)(ws + off); off = WS_ALIGN(off + (size_t)N * 256 * 2);
    ushort* h1    = (ushort*)(ws + off); off = WS_ALIGN(off + (size_t)N * 256 * 2);
    ushort* zl    = (ushort*)(ws + off); off = WS_ALIGN(off + (size_t)N * 128 * 2);
    ushort* zr    = (ushort*)(ws + off); off = WS_ALIGN(off + (size_t)N * 128 * 2);
    ushort* Wc1   = (ushort*)(ws + off); off = WS_ALIGN(off + (size_t)512 * 512 * 2);
    ushort* Wc2   = (ushort*)(ws + off); off = WS_ALIGN(off + (size_t)256 * 256 * 2);
    float*  Pp    = (float*)(ws + off);  off = WS_ALIGN(off + (size_t)N * 32 * 4);

    const int* src = ei;
    const int* dst = ei + E;

    hipMemsetAsync(deg, 0, (size_t)N * 4, stream);
    hipMemsetAsync(cursor, 0, (size_t)N * 4, stream);

    int eb = (E + 255) / 256;
    int nb = (N + 1023) / 1024;   // <= 256
    hist_kernel<<<eb, 256, 0, stream>>>(dst, deg, E);
    scan_phase1<<<nb, 256, 0, stream>>>(deg, bsum, N);
    scan_phase2<<<1, 256, 0, stream>>>(bsum, rowptr, nb, N);
    scan_phase3<<<nb, 256, 0, stream>>>(deg, bsum, rowptr, N);
    scatter_kernel<<<eb, 256, 0, stream>>>(src, dst, rowptr, cursor, adj, E);

    build_wcat<<<((512 * 512 + 256 * 256) / 8 + 255) / 256, 256, 0, stream>>>(
        W1l, W1r, W2l, W2r, Wc1, Wc2);

    int gm = (N + 127) / 128;   // 391

    // layer 1: [Yl|Yr] = bf16(x) @ Wc1^T  (fused pipelined cast, [N,256] each)
    gemm_wide<true><<<dim3(2, gm), 512, 0, stream>>>(
        x, (const ushort*)nullptr, Wc1, Yl, Yr, N, 512, 512, 256);
    // h1 = relu(mean + self + b1)  [N,256] bf16 (32 lanes/node, 16B loads)
    aggregate_bf16<32><<<(N + 7) / 8, 256, 0, stream>>>(Yl, Yr, b1, rowptr, adj, h1, N);

    // layer 2: [zl|zr] = h1 @ Wc2^T   ([N,128] each)
    gemm_wide<false><<<dim3(1, gm), 512, 0, stream>>>(
        (const float*)nullptr, h1, Wc2, zl, zr, N, 256, 256, 128);
    // h2  [N,128] bf16 (reuse Yl; 16 lanes/node)
    ushort* h2 = Yl;
    aggregate_bf16<16><<<(N + 15) / 16, 256, 0, stream>>>(zl, zr, b2, rowptr, adj, h2, N);

    // params p = h2 @ Wp^T + bp -> P [N,32] fp32 (8 lanes/node)
    params_kernel<<<(N + 31) / 32, 256, 0, stream>>>(h2, Wp, bp, Pp, N);
    // Cayley -> out [N,8,8] fp32
    cayley_kernel<<<(N + 255) / 256, 256, 0, stream>>>(Pp, out, N);
}